// Round 5
// baseline (1707.347 us; speedup 1.0000x reference)
//
#include <hip/hip_runtime.h>

typedef __fp16 h2 __attribute__((ext_vector_type(2)));
typedef __fp16 h4 __attribute__((ext_vector_type(4)));
typedef __fp16 h8 __attribute__((ext_vector_type(8)));
typedef float  f32x4 __attribute__((ext_vector_type(4)));

#define TT 2048
#define HH 64
#define NL 8
#define NB 256
#define NBLK 16            // batches per block (one MFMA N-tile)
#define NGRID (NB/NBLK)    // 16 blocks

union H8U { h8 v; h2 p[4]; };

__device__ __forceinline__ float tanh_fast(float v){
    // tanh(x) = 1 - 2/(exp(2x)+1)
    float e = __expf(2.0f * v);
    float r = __builtin_amdgcn_rcpf(e + 1.0f);
    return fmaf(-2.0f, r, 1.0f);
}

__device__ __forceinline__ void barrier_lgkm_only(){
    asm volatile("" ::: "memory");
    __builtin_amdgcn_s_waitcnt(0xc07f);            // lgkmcnt(0), vmcnt/expcnt = max
    __builtin_amdgcn_s_barrier();
    asm volatile("" ::: "memory");
}

// ---------------------------------------------------------------------------
// H buffers in LDS: [layer 0..8][phase 0..1][n=16 rows][k=64 f16].
// Row stride 128 B. Within a row, 16-B chunks are XOR-swizzled by (n&7) so
// the per-lane b128/b64 accesses spread uniformly over banks.
// chunk(k) = k/8 (8 f16 per 16-B chunk); stored chunk index = chunk ^ (n&7).
//
// Fragment conventions (k-permutation-invariance: A and B use the SAME
// (lane,slot)->k map, so the HW's internal k layout cancels in A*B):
//   A-frag (16x32 tile mt,kt): lane l holds A[mt*16 + (l&15)][kt*32 + (l>>4)*8 + s]
//   B-frag (32x16 tile kt):    lane l holds B[kt*32 + (l>>4)*8 + s][l&15]
//   C (HW-verified m89):       reg r = C[mt*16 + (l>>4)*4 + r][l&15]
// ---------------------------------------------------------------------------

#define STEP(N, PR, PW, XR) { \
    const int t = (N) - wv; \
    const bool active = (t >= 0) & (t < TT); \
    const int base_inp = (wv*2 + (PR))*2048; \
    const int base_h   = ((wv+1)*2 + (PR))*2048; \
    H8U bh[2], binp[2]; \
    _Pragma("unroll") \
    for (int kt = 0; kt < 2; ++kt) \
        bh[kt].v = *(const h8*)(HB + base_h + nn*128 + (((kt*4 + g) ^ (nn&7))*16)); \
    if (wv == 0){ \
        _Pragma("unroll") \
        for (int kt = 0; kt < 2; ++kt) \
            _Pragma("unroll") \
            for (int pp = 0; pp < 4; ++pp) \
                binp[kt].p[pp] = __builtin_amdgcn_cvt_pkrtz( \
                    XR[kt*2 + (pp>>1)][(pp&1)*2], XR[kt*2 + (pp>>1)][(pp&1)*2 + 1]); \
    } else { \
        _Pragma("unroll") \
        for (int kt = 0; kt < 2; ++kt) \
            binp[kt].v = *(const h8*)(HB + base_inp + nn*128 + (((kt*4 + g) ^ (nn&7))*16)); \
    } \
    f32x4 acc[4]; \
    _Pragma("unroll") \
    for (int mt = 0; mt < 4; ++mt){ \
        acc[mt][0] = bias[mt][0]; acc[mt][1] = bias[mt][1]; \
        acc[mt][2] = bias[mt][2]; acc[mt][3] = bias[mt][3]; \
    } \
    _Pragma("unroll") \
    for (int mt = 0; mt < 4; ++mt){ \
        _Pragma("unroll") \
        for (int kt = 0; kt < 2; ++kt){ \
            acc[mt] = __builtin_amdgcn_mfma_f32_16x16x32_f16(whhA[mt][kt].v, bh[kt].v,   acc[mt], 0, 0, 0); \
            acc[mt] = __builtin_amdgcn_mfma_f32_16x16x32_f16(wihA[mt][kt].v, binp[kt].v, acc[mt], 0, 0, 0); \
        } \
    } \
    if (wv == 7){ \
        f32x4 accy = { (g == 0) ? bout : 0.f, 0.f, 0.f, 0.f }; \
        accy = __builtin_amdgcn_mfma_f32_16x16x32_f16(woutA[0].v, bh[0].v, accy, 0, 0, 0); \
        accy = __builtin_amdgcn_mfma_f32_16x16x32_f16(woutA[1].v, bh[1].v, accy, 0, 0, 0); \
        const int ty = (N) - 8; \
        if (ty >= 0 && g == 0) yout[(size_t)(bbase + nn)*TT + ty] = accy[0]; \
    } \
    float hn[4][4]; \
    _Pragma("unroll") \
    for (int mt = 0; mt < 4; ++mt){ \
        hn[mt][0] = tanh_fast(acc[mt][0]); hn[mt][1] = tanh_fast(acc[mt][1]); \
        hn[mt][2] = tanh_fast(acc[mt][2]); hn[mt][3] = tanh_fast(acc[mt][3]); \
    } \
    if (active){ \
        const int base_w = ((wv+1)*2 + (PW))*2048; \
        _Pragma("unroll") \
        for (int mt = 0; mt < 4; ++mt){ \
            h2 lo = __builtin_amdgcn_cvt_pkrtz(hn[mt][0], hn[mt][1]); \
            h2 hi = __builtin_amdgcn_cvt_pkrtz(hn[mt][2], hn[mt][3]); \
            h4 w4; w4[0] = lo[0]; w4[1] = lo[1]; w4[2] = hi[0]; w4[3] = hi[1]; \
            const int cc = mt*2 + (g>>1); \
            *(h4*)(HB + base_w + nn*128 + ((cc ^ (nn&7))*16) + (g&1)*8) = w4; \
        } \
        if (t == TT-1){ \
            _Pragma("unroll") \
            for (int mt = 0; mt < 4; ++mt){ \
                f32x4 st; st[0]=hn[mt][0]; st[1]=hn[mt][1]; st[2]=hn[mt][2]; st[3]=hn[mt][3]; \
                *(f32x4*)(hout + ((size_t)wv*NB + bbase + nn)*HH + mt*16 + g*4) = st; \
            } \
        } \
    } \
    if (wv == 0){ \
        const int t2 = (N) + 2; \
        if (t2 < TT){ \
            const float* xb = x + ((size_t)(bbase + nn)*TT + t2)*HH + g*8; \
            XR[0] = *(const f32x4*)(xb);      XR[1] = *(const f32x4*)(xb + 4); \
            XR[2] = *(const f32x4*)(xb + 32); XR[3] = *(const f32x4*)(xb + 36); \
        } \
    } \
    barrier_lgkm_only(); \
}

__global__ void __launch_bounds__(512) rnn_kernel(
    const float* __restrict__ x,        // [B,T,64]
    const float* __restrict__ h_state,  // [8,B,64]
    const float* __restrict__ W_ih0,    // [64,64]
    const float* __restrict__ W_ih,     // [7,64,64]
    const float* __restrict__ W_hh,     // [8,64,64]
    const float* __restrict__ b_ih,     // [8,64]
    const float* __restrict__ b_hh,     // [8,64]
    const float* __restrict__ W_out,    // [1,64]
    const float* __restrict__ b_out,    // [1]
    float* __restrict__ out)            // y[256*2048] ++ h_final[8*256*64]
{
    __shared__ __attribute__((aligned(16))) __fp16 Hbuf[9*2*16*64];
    char* HB = (char*)Hbuf;
    const int tid  = threadIdx.x;
    const int wv   = tid >> 6;          // wave id == layer id
    const int lane = tid & 63;
    const int g    = lane >> 4;         // lane group (k-chunk selector)
    const int nn   = lane & 15;         // A row within tile / B,C column (batch)
    const int bbase = blockIdx.x * NBLK;

    // ---- A-fragments for W_ih and W_hh (f16, k-map = kt*32 + g*8 + s)
    H8U wihA[4][2], whhA[4][2];
    const float* Wi = (wv == 0) ? W_ih0 : (W_ih + (size_t)(wv-1)*HH*HH);
    const float* Wh = W_hh + (size_t)wv*HH*HH;
    #pragma unroll
    for (int mt = 0; mt < 4; ++mt){
        #pragma unroll
        for (int kt = 0; kt < 2; ++kt){
            const float* pi = Wi + (size_t)(mt*16 + nn)*HH + kt*32 + g*8;
            const float* ph = Wh + (size_t)(mt*16 + nn)*HH + kt*32 + g*8;
            f32x4 i0 = *(const f32x4*)(pi), i1 = *(const f32x4*)(pi + 4);
            f32x4 h0 = *(const f32x4*)(ph), h1 = *(const f32x4*)(ph + 4);
            wihA[mt][kt].p[0] = __builtin_amdgcn_cvt_pkrtz(i0[0], i0[1]);
            wihA[mt][kt].p[1] = __builtin_amdgcn_cvt_pkrtz(i0[2], i0[3]);
            wihA[mt][kt].p[2] = __builtin_amdgcn_cvt_pkrtz(i1[0], i1[1]);
            wihA[mt][kt].p[3] = __builtin_amdgcn_cvt_pkrtz(i1[2], i1[3]);
            whhA[mt][kt].p[0] = __builtin_amdgcn_cvt_pkrtz(h0[0], h0[1]);
            whhA[mt][kt].p[1] = __builtin_amdgcn_cvt_pkrtz(h0[2], h0[3]);
            whhA[mt][kt].p[2] = __builtin_amdgcn_cvt_pkrtz(h1[0], h1[1]);
            whhA[mt][kt].p[3] = __builtin_amdgcn_cvt_pkrtz(h1[2], h1[3]);
        }
    }

    // ---- bias per C element (C map: row = mt*16 + g*4 + r, verified m89)
    float bias[4][4];
    #pragma unroll
    for (int mt = 0; mt < 4; ++mt)
        #pragma unroll
        for (int r = 0; r < 4; ++r){
            const int row = mt*16 + g*4 + r;
            bias[mt][r] = b_ih[wv*HH + row] + b_hh[wv*HH + row];
        }

    // ---- wave 7: W_out as A row 0 (rows 1..15 zero), + b_out
    H8U woutA[2]; float bout = 0.f;
    if (wv == 7){
        #pragma unroll
        for (int kt = 0; kt < 2; ++kt)
            #pragma unroll
            for (int q = 0; q < 4; ++q){
                float a0 = (nn == 0) ? W_out[kt*32 + g*8 + q*2]     : 0.f;
                float a1 = (nn == 0) ? W_out[kt*32 + g*8 + q*2 + 1] : 0.f;
                woutA[kt].p[q] = __builtin_amdgcn_cvt_pkrtz(a0, a1);
            }
        bout = b_out[0];
    }

    // ---- zero all H buffers, then place initial h_state
    for (int i = tid; i < 9*2*16*64; i += 512) Hbuf[i] = (__fp16)0.f;
    __syncthreads();
    {
        // wave l first reads its own h at n=l from phase (l+1)&1
        const int base = ((wv+1)*2 + ((wv+1)&1)) * 2048;
        #pragma unroll
        for (int n2 = 0; n2 < NBLK; ++n2){
            float hv = h_state[((size_t)wv*NB + bbase + n2)*HH + lane];
            const int byte = base + n2*128 + (((lane>>3) ^ (n2&7))*16) + (lane&7)*2;
            *(__fp16*)(HB + byte) = (__fp16)hv;
        }
    }

    // ---- x B-frag prefetch ring (wave 0), f32, 2 timesteps deep
    f32x4 xr0[4], xr1[4];
    #pragma unroll
    for (int c = 0; c < 4; ++c){
        xr0[c] = f32x4{0.f, 0.f, 0.f, 0.f};
        xr1[c] = f32x4{0.f, 0.f, 0.f, 0.f};
    }
    if (wv == 0){
        const float* xb0 = x + ((size_t)(bbase + nn)*TT + 0)*HH + g*8;
        xr0[0] = *(const f32x4*)(xb0);      xr0[1] = *(const f32x4*)(xb0 + 4);
        xr0[2] = *(const f32x4*)(xb0 + 32); xr0[3] = *(const f32x4*)(xb0 + 36);
        const float* xb1 = x + ((size_t)(bbase + nn)*TT + 1)*HH + g*8;
        xr1[0] = *(const f32x4*)(xb1);      xr1[1] = *(const f32x4*)(xb1 + 4);
        xr1[2] = *(const f32x4*)(xb1 + 32); xr1[3] = *(const f32x4*)(xb1 + 36);
    }
    __syncthreads();

    float* yout = out;                    // [B*T]
    float* hout = out + (size_t)NB*TT;    // [8,B,64]

    for (int n2 = 0; n2 < TT + NL; n2 += 2){
        STEP(n2,     1, 0, xr0)
        STEP(n2 + 1, 0, 1, xr1)
    }
}

extern "C" void kernel_launch(void* const* d_in, const int* in_sizes, int n_in,
                              void* d_out, int out_size, void* d_ws, size_t ws_size,
                              hipStream_t stream) {
    (void)in_sizes; (void)n_in; (void)d_ws; (void)ws_size; (void)out_size;
    const float* x       = (const float*)d_in[0];
    const float* h_state = (const float*)d_in[1];
    const float* W_ih0   = (const float*)d_in[2];
    const float* W_ih    = (const float*)d_in[3];
    const float* W_hh    = (const float*)d_in[4];
    const float* b_ih    = (const float*)d_in[5];
    const float* b_hh    = (const float*)d_in[6];
    const float* W_out   = (const float*)d_in[7];
    const float* b_out   = (const float*)d_in[8];
    float* out = (float*)d_out;

    rnn_kernel<<<dim3(NGRID), dim3(512), 0, stream>>>(
        x, h_state, W_ih0, W_ih, W_hh, b_ih, b_hh, W_out, b_out, out);
}

// Round 6
// 914.277 us; speedup vs baseline: 1.8674x; 1.8674x over previous
//
#include <hip/hip_runtime.h>

typedef _Float16 h2 __attribute__((ext_vector_type(2)));
typedef _Float16 h8 __attribute__((ext_vector_type(8)));

#define TT 2048
#define HH 64
#define NL 8
#define NB 256
#define G  8            // timesteps per barrier interval
#define NCH (TT/G)      // 256 chunks per layer
#define NI  (NCH + NL)  // 264 intervals (includes pipeline fill/drain)

union HU { h8 v; h2 p[4]; };

__device__ __forceinline__ float tanh_fast(float v){
    // tanh(x) = 1 - 2/(exp(2x)+1); exp via fast hw path, rcp via v_rcp_f32
    float e = __expf(2.0f * v);
    float r = __builtin_amdgcn_rcpf(e + 1.0f);
    return fmaf(-2.0f, r, 1.0f);
}

// Barrier draining ONLY lgkm: wave-0 x prefetch loads and wave-7 y stores
// stay in flight across intervals.
__device__ __forceinline__ void barrier_lgkm_only(){
    asm volatile("" ::: "memory");
    __builtin_amdgcn_s_waitcnt(0xc07f);            // lgkmcnt(0), vmcnt/expcnt = max
    __builtin_amdgcn_s_barrier();
    asm volatile("" ::: "memory");
}

// ---------------------------------------------------------------------------
// Chunked wavefront pipeline: wave l = layer l, interval m covers its
// timesteps t = (m-l)*G + j, j=0..G-1. Boundary queues in LDS:
//   buf[boundary 0..8][phase 0..1][slot 0..G-1][64 f16]
// Interval m: read phase P = 1-(m&1), write phase 1-P = m&1.
//  - binp slots buf[l][P][j] were written by wave l-1 during interval m-1.
//  - self h: wave writes hn to buf[l+1][1-P][j]; step j+1 reads it back
//    (same-wave RAW through __shared__ — compiler orders, no barrier).
//    Step j=0 reads buf[l+1][P][G-1] (own write from interval m-1).
//  - boundary 0 = x: wave 0 writes x for interval m+1 into buf[0][1-P][*]
//    from a 2-interval-deep register ring (global loads survive the
//    lgkm-only barriers by design).
// One barrier per interval: 264 instead of 2056.
// ---------------------------------------------------------------------------

#define INTERVAL(MM, P, XC, XN) { \
    const int mm = (MM); \
    if ((unsigned)(mm - wv) < (unsigned)NCH) { \
        if (wv == 0){ \
            if (mm + 1 < NCH){ \
                _Pragma("unroll") \
                for (int j = 0; j < G; ++j) \
                    buf[0][1-(P)][j][lane] = (_Float16)XC[j]; \
            } \
            if (mm + 2 < NCH){ \
                _Pragma("unroll") \
                for (int j = 0; j < G; ++j) \
                    XN[j] = x[((size_t)b*TT + (mm+2)*G + j)*HH + lane]; \
            } \
        } \
        _Pragma("unroll") \
        for (int j = 0; j < G; ++j){ \
            const h8* ib = (const h8*)&buf[wv][P][j][0]; \
            const h8* hb = (j == 0) ? (const h8*)&buf[wv+1][P][G-1][0] \
                                    : (const h8*)&buf[wv+1][1-(P)][j-1][0]; \
            float a0 = bsum, a1 = 0.f; \
            HU hvs[8]; \
            _Pragma("unroll") \
            for (int u = 0; u < 8; ++u){ \
                HU iu, hu; \
                iu.v = ib[u];              /* broadcast ds_read_b128 */ \
                hu.v = hb[u]; \
                hvs[u] = hu; \
                _Pragma("unroll") \
                for (int k = 0; k < 4; ++k){ \
                    a0 = __builtin_amdgcn_fdot2(wih[u*4 + k], iu.p[k], a0, false); \
                    a1 = __builtin_amdgcn_fdot2(whh[u*4 + k], hu.p[k], a1, false); \
                } \
            } \
            float hn = tanh_fast(a0 + a1); \
            if (wv == 7){ \
                float ys = bout; \
                _Pragma("unroll") \
                for (int u = 0; u < 8; ++u) \
                    _Pragma("unroll") \
                    for (int k = 0; k < 4; ++k) \
                        ys = __builtin_amdgcn_fdot2(wout2[u*4 + k], hvs[u].p[k], ys, false); \
                const int ty = (mm - 7)*G + j - 1; \
                if (ty >= 0 && lane == 0) yout[(size_t)b*TT + ty] = ys; \
            } \
            buf[wv+1][1-(P)][j][lane] = (_Float16)hn; \
            if (mm - wv == NCH-1 && j == G-1) \
                hout[((size_t)wv*NB + b)*HH + lane] = hn; \
        } \
    } \
    barrier_lgkm_only(); \
}

__global__ void __launch_bounds__(512) rnn_kernel(
    const float* __restrict__ x,        // [B,T,64]
    const float* __restrict__ h_state,  // [8,B,64]
    const float* __restrict__ W_ih0,    // [64,64]
    const float* __restrict__ W_ih,     // [7,64,64]
    const float* __restrict__ W_hh,     // [8,64,64]
    const float* __restrict__ b_ih,     // [8,64]
    const float* __restrict__ b_hh,     // [8,64]
    const float* __restrict__ W_out,    // [1,64]
    const float* __restrict__ b_out,    // [1]
    float* __restrict__ out)            // y[256*2048] ++ h_final[8*256*64]
{
    __shared__ __attribute__((aligned(16))) _Float16 buf[NL+1][2][G][HH];
    const int tid  = threadIdx.x;
    const int wv   = tid >> 6;     // wave id == layer id
    const int lane = tid & 63;
    const size_t b = blockIdx.x;

    // ---- load this layer's weights into registers (packed f16 pairs, row = lane)
    h2 wih[32], whh[32], wout2[32];
    const float2* wi = (const float2*)(wv == 0 ? W_ih0 : (W_ih + (size_t)(wv-1)*HH*HH));
    const float2* wh = (const float2*)(W_hh + (size_t)wv*HH*HH);
    #pragma unroll
    for (int i = 0; i < 32; ++i){
        float2 a = wi[lane*32 + i];
        float2 c = wh[lane*32 + i];
        wih[i] = h2{(_Float16)a.x, (_Float16)a.y};
        whh[i] = h2{(_Float16)c.x, (_Float16)c.y};
    }
    float bsum = b_ih[wv*HH + lane] + b_hh[wv*HH + lane];
    float bout = 0.f;
    if (wv == 7){
        const float2* wo = (const float2*)W_out;
        #pragma unroll
        for (int i = 0; i < 32; ++i){
            float2 a = wo[i];
            wout2[i] = h2{(_Float16)a.x, (_Float16)a.y};
        }
        bout = b_out[0];
    }

    // ---- zero queues, place initial state + first x chunk
    for (int i = tid; i < (NL+1)*2*G*HH; i += 512) ((_Float16*)buf)[i] = (_Float16)0.f;
    __syncthreads();
    // wave l's first interval is m=l (read phase 1-(l&1)); j=0 reads slot G-1
    buf[wv+1][1-(wv&1)][G-1][lane] = (_Float16)h_state[((size_t)wv*NB + b)*HH + lane];
    float xa[G], xb[G];
    if (wv == 0){
        #pragma unroll
        for (int j = 0; j < G; ++j){
            buf[0][1][j][lane] = (_Float16)x[((size_t)b*TT + j)*HH + lane]; // t=0..7, read at m=0
            xa[j] = x[((size_t)b*TT + G + j)*HH + lane];                   // t=8..15, staged during m=0
        }
    }
    __syncthreads();

    float* yout = out;                    // [B*T]
    float* hout = out + (size_t)NB*TT;    // [8,B,64]

    for (int m2 = 0; m2 < NI; m2 += 2){
        INTERVAL(m2,     1, xa, xb)
        INTERVAL(m2 + 1, 0, xb, xa)
    }

    // ---- epilogue: y[TT-1] from h7[TT-1] (written during m=262, phase 0, slot G-1)
    if (wv == 7){
        const h8* hb = (const h8*)&buf[8][0][G-1][0];
        float ys = bout;
        #pragma unroll
        for (int u = 0; u < 8; ++u){
            HU hu; hu.v = hb[u];
            #pragma unroll
            for (int k = 0; k < 4; ++k)
                ys = __builtin_amdgcn_fdot2(wout2[u*4 + k], hu.p[k], ys, false);
        }
        if (lane == 0) yout[(size_t)b*TT + (TT-1)] = ys;
    }
}

extern "C" void kernel_launch(void* const* d_in, const int* in_sizes, int n_in,
                              void* d_out, int out_size, void* d_ws, size_t ws_size,
                              hipStream_t stream) {
    (void)in_sizes; (void)n_in; (void)d_ws; (void)ws_size; (void)out_size;
    const float* x       = (const float*)d_in[0];
    const float* h_state = (const float*)d_in[1];
    const float* W_ih0   = (const float*)d_in[2];
    const float* W_ih    = (const float*)d_in[3];
    const float* W_hh    = (const float*)d_in[4];
    const float* b_ih    = (const float*)d_in[5];
    const float* b_hh    = (const float*)d_in[6];
    const float* W_out   = (const float*)d_in[7];
    const float* b_out   = (const float*)d_in[8];
    float* out = (float*)d_out;

    rnn_kernel<<<dim3(NB), dim3(512), 0, stream>>>(
        x, h_state, W_ih0, W_ih, W_hh, b_ih, b_hh, W_out, b_out, out);
}

// Round 7
// 638.584 us; speedup vs baseline: 2.6736x; 1.4317x over previous
//
#include <hip/hip_runtime.h>

typedef _Float16 h2 __attribute__((ext_vector_type(2)));
typedef _Float16 h8 __attribute__((ext_vector_type(8)));
typedef __fp16   g2 __attribute__((ext_vector_type(2)));
typedef __fp16   g8 __attribute__((ext_vector_type(8)));
typedef float    f32x4 __attribute__((ext_vector_type(4)));

#define TT 2048
#define HH 64
#define NL 8
#define NB 256
#define G  8            // timesteps per barrier interval
#define NCH (TT/G)      // 256 chunks per layer
#define NI  (NCH + NL)  // 264 intervals

union HU { h8 v; h2 p[4]; };
union GU { g8 v; g2 p[4]; h8 h; };   // bitcast LDS (_Float16) <-> MFMA (__fp16)

__device__ __forceinline__ float tanh_fast(float v){
    // tanh(x) = 1 - 2/(exp(2x)+1)
    float e = __expf(2.0f * v);
    float r = __builtin_amdgcn_rcpf(e + 1.0f);
    return fmaf(-2.0f, r, 1.0f);
}

// Barrier draining ONLY lgkm: wave-0 x prefetch loads and y stores stay in
// flight across intervals.
__device__ __forceinline__ void barrier_lgkm_only(){
    asm volatile("" ::: "memory");
    __builtin_amdgcn_s_waitcnt(0xc07f);            // lgkmcnt(0), vmcnt/expcnt = max
    __builtin_amdgcn_s_barrier();
    asm volatile("" ::: "memory");
}

// ---------------------------------------------------------------------------
// Chunked wavefront pipeline (R6 structure) + two changes:
//  1. W_ih·inp for all 8 slots of an interval is ONE 8-column GEMM on the
//     MFMA pipe (8 x mfma_f32_16x16x32_f16), spilled to padded LDS scratch
//     pre[wv][row][slot]; each serial step reads back 1 f32. This moves
//     half the per-step fdot2 issue off the VALU.
//  2. y-projection rebalanced: wave w computes y for slot w of chunk m-8
//     (32 fdot2/interval) instead of wave 7 doing all 8 slots.
// Fragment conventions verbatim from the verified R5 kernel:
//   A-frag: lane(g,nn) holds A[mt*16+nn][kt*32+g*8+s]
//   B-frag: lane(g,nn) holds B[kt*32+g*8+s][col=nn]   (same k-map -> cancels)
//   C (m89): reg r = C[mt*16+g*4+r][col=nn]
// B cols 8..15 read garbage (in-bounds) -> contaminate only unspilled C cols.
// ---------------------------------------------------------------------------

#define INTERVAL(MM, P, XC, XN) { \
    const int mm = (MM); \
    const bool act = (unsigned)(mm - wv) < (unsigned)NCH; \
    if (wv == 0){ \
        if (mm + 1 < NCH){ \
            _Pragma("unroll") \
            for (int j = 0; j < G; ++j) \
                buf[0][1-(P)][j][lane] = (_Float16)XC[j]; \
        } \
        if (mm + 2 < NCH){ \
            _Pragma("unroll") \
            for (int j = 0; j < G; ++j) \
                XN[j] = x[((size_t)b*TT + (mm+2)*G + j)*HH + lane]; \
        } \
    } \
    if (mm >= 8){ \
        /* y for chunk mm-8, slot wv (written by wave 7 last interval, phase P) */ \
        const h8* hy = (const h8*)&buf[8][P][wv][0]; \
        float y0 = bout, y1 = 0.f; \
        _Pragma("unroll") \
        for (int u = 0; u < 8; ++u){ \
            HU hu; hu.v = hy[u]; \
            y0 = __builtin_amdgcn_fdot2(wout2[u*4+0], hu.p[0], y0, false); \
            y1 = __builtin_amdgcn_fdot2(wout2[u*4+1], hu.p[1], y1, false); \
            y0 = __builtin_amdgcn_fdot2(wout2[u*4+2], hu.p[2], y0, false); \
            y1 = __builtin_amdgcn_fdot2(wout2[u*4+3], hu.p[3], y1, false); \
        } \
        if (lane == 0) yout[(size_t)b*TT + (mm-8)*G + wv] = y0 + y1; \
    } \
    if (act){ \
        /* ---- x-projection GEMM: pre[row][slot] = W_ih · inp[slot] ---- */ \
        const _Float16* bp = &buf[wv][P][0][0] + nn*HH + g*8; \
        GU bx0, bx1; \
        bx0.h = *(const h8*)(bp); \
        bx1.h = *(const h8*)(bp + 32); \
        _Pragma("unroll") \
        for (int mt = 0; mt < 4; ++mt){ \
            f32x4 a = {0.f, 0.f, 0.f, 0.f}; \
            a = __builtin_amdgcn_mfma_f32_16x16x32_f16(wihA[mt][0].v, bx0.v, a, 0, 0, 0); \
            a = __builtin_amdgcn_mfma_f32_16x16x32_f16(wihA[mt][1].v, bx1.v, a, 0, 0, 0); \
            if (nn < 8){ \
                _Pragma("unroll") \
                for (int r = 0; r < 4; ++r) \
                    pre[wv][mt*16 + g*4 + r][nn] = a[r]; \
            } \
        } \
        /* ---- 8 serial steps: W_hh·h recurrence via fdot2 ---- */ \
        _Pragma("unroll") \
        for (int j = 0; j < G; ++j){ \
            const h8* hb = (j == 0) ? (const h8*)&buf[wv+1][P][G-1][0] \
                                    : (const h8*)&buf[wv+1][1-(P)][j-1][0]; \
            float a0 = bsum + pre[wv][lane][j], a1 = 0.f; \
            _Pragma("unroll") \
            for (int u = 0; u < 8; ++u){ \
                HU hu; hu.v = hb[u];            /* broadcast ds_read_b128 */ \
                a0 = __builtin_amdgcn_fdot2(whh[u*4+0], hu.p[0], a0, false); \
                a1 = __builtin_amdgcn_fdot2(whh[u*4+1], hu.p[1], a1, false); \
                a0 = __builtin_amdgcn_fdot2(whh[u*4+2], hu.p[2], a0, false); \
                a1 = __builtin_amdgcn_fdot2(whh[u*4+3], hu.p[3], a1, false); \
            } \
            float hn = tanh_fast(a0 + a1); \
            buf[wv+1][1-(P)][j][lane] = (_Float16)hn; \
            if (mm - wv == NCH-1 && j == G-1) \
                hout[((size_t)wv*NB + b)*HH + lane] = hn; \
        } \
    } \
    barrier_lgkm_only(); \
}

__global__ void __launch_bounds__(512) rnn_kernel(
    const float* __restrict__ x,        // [B,T,64]
    const float* __restrict__ h_state,  // [8,B,64]
    const float* __restrict__ W_ih0,    // [64,64]
    const float* __restrict__ W_ih,     // [7,64,64]
    const float* __restrict__ W_hh,     // [8,64,64]
    const float* __restrict__ b_ih,     // [8,64]
    const float* __restrict__ b_hh,     // [8,64]
    const float* __restrict__ W_out,    // [1,64]
    const float* __restrict__ b_out,    // [1]
    float* __restrict__ out)            // y[256*2048] ++ h_final[8*256*64]
{
    __shared__ __attribute__((aligned(16))) _Float16 buf[NL+1][2][G][HH];  // 18 KB
    __shared__ __attribute__((aligned(16))) float pre[NL][HH][G+1];        // 18.4 KB (pad 9 breaks bank stride)
    const int tid  = threadIdx.x;
    const int wv   = tid >> 6;     // wave id == layer id
    const int lane = tid & 63;
    const int g    = lane >> 4;    // MFMA lane group (k-chunk)
    const int nn   = lane & 15;    // MFMA A-row-in-tile / B,C column
    const size_t b = blockIdx.x;

    // ---- W_hh rows for fdot (lane = row), packed f16 pairs
    h2 whh[32], wout2[32];
    const float2* wh = (const float2*)(W_hh + (size_t)wv*HH*HH);
    #pragma unroll
    for (int i = 0; i < 32; ++i){
        float2 c = wh[lane*32 + i];
        whh[i] = h2{(_Float16)c.x, (_Float16)c.y};
    }
    // ---- W_out (all waves now — y is distributed across waves)
    {
        const float2* wo = (const float2*)W_out;
        #pragma unroll
        for (int i = 0; i < 32; ++i){
            float2 a = wo[i];
            wout2[i] = h2{(_Float16)a.x, (_Float16)a.y};
        }
    }
    float bout = b_out[0];
    float bsum = b_ih[wv*HH + lane] + b_hh[wv*HH + lane];

    // ---- W_ih A-fragments for the x-projection MFMA (R5-verified layout)
    GU wihA[4][2];
    const float* Wi = (wv == 0) ? W_ih0 : (W_ih + (size_t)(wv-1)*HH*HH);
    #pragma unroll
    for (int mt = 0; mt < 4; ++mt){
        #pragma unroll
        for (int kt = 0; kt < 2; ++kt){
            const float* pi = Wi + (size_t)(mt*16 + nn)*HH + kt*32 + g*8;
            f32x4 i0 = *(const f32x4*)(pi), i1 = *(const f32x4*)(pi + 4);
            wihA[mt][kt].p[0] = __builtin_amdgcn_cvt_pkrtz(i0[0], i0[1]);
            wihA[mt][kt].p[1] = __builtin_amdgcn_cvt_pkrtz(i0[2], i0[3]);
            wihA[mt][kt].p[2] = __builtin_amdgcn_cvt_pkrtz(i1[0], i1[1]);
            wihA[mt][kt].p[3] = __builtin_amdgcn_cvt_pkrtz(i1[2], i1[3]);
        }
    }

    // ---- zero queues, place initial state + first x chunk
    for (int i = tid; i < (NL+1)*2*G*HH; i += 512) ((_Float16*)buf)[i] = (_Float16)0.f;
    __syncthreads();
    // wave l's first interval is m=l (read phase 1-(l&1)); j=0 reads slot G-1
    buf[wv+1][1-(wv&1)][G-1][lane] = (_Float16)h_state[((size_t)wv*NB + b)*HH + lane];
    float xa[G], xb[G];
    if (wv == 0){
        #pragma unroll
        for (int j = 0; j < G; ++j){
            buf[0][1][j][lane] = (_Float16)x[((size_t)b*TT + j)*HH + lane]; // t=0..7, read at m=0
            xa[j] = x[((size_t)b*TT + G + j)*HH + lane];                   // t=8..15, staged during m=0
        }
    }
    __syncthreads();

    float* yout = out;                    // [B*T]
    float* hout = out + (size_t)NB*TT;    // [8,B,64]

    for (int m2 = 0; m2 < NI; m2 += 2){
        INTERVAL(m2,     1, xa, xb)
        INTERVAL(m2 + 1, 0, xb, xa)
    }
    // no epilogue: interval m=NI-1 emits y for the final chunk (slots 0..7)
}

extern "C" void kernel_launch(void* const* d_in, const int* in_sizes, int n_in,
                              void* d_out, int out_size, void* d_ws, size_t ws_size,
                              hipStream_t stream) {
    (void)in_sizes; (void)n_in; (void)d_ws; (void)ws_size; (void)out_size;
    const float* x       = (const float*)d_in[0];
    const float* h_state = (const float*)d_in[1];
    const float* W_ih0   = (const float*)d_in[2];
    const float* W_ih    = (const float*)d_in[3];
    const float* W_hh    = (const float*)d_in[4];
    const float* b_ih    = (const float*)d_in[5];
    const float* b_hh    = (const float*)d_in[6];
    const float* W_out   = (const float*)d_in[7];
    const float* b_out   = (const float*)d_in[8];
    float* out = (float*)d_out;

    rnn_kernel<<<dim3(NB), dim3(512), 0, stream>>>(
        x, h_state, W_ih0, W_ih, W_hh, b_ih, b_hh, W_out, b_out, out);
}

// Round 8
// 624.851 us; speedup vs baseline: 2.7324x; 1.0220x over previous
//
#include <hip/hip_runtime.h>

typedef _Float16 h2 __attribute__((ext_vector_type(2)));
typedef _Float16 h8 __attribute__((ext_vector_type(8)));
typedef __fp16   g2 __attribute__((ext_vector_type(2)));
typedef __fp16   g8 __attribute__((ext_vector_type(8)));
typedef float    f32x4 __attribute__((ext_vector_type(4)));

#define TT 2048
#define HH 64
#define NL 8
#define NB 256
#define G  8            // timesteps per barrier interval
#define NCH (TT/G)      // 256 chunks per layer
#define NI  (NCH + NL)  // 264 intervals

union HU { h8 v; h2 p[4]; };
union GU { g8 v; g2 p[4]; h8 h; };   // bitcast LDS (_Float16) <-> MFMA (__fp16)

// buf byte layout: boundary l (0..8), phase P (0..1), slot j (0..7), 64 f16.
// Within a slot row (128 B), the 16-B chunk c is stored at index c^j (T2
// XOR swizzle): the MFMA B-frag read (16 lanes at 128-B stride) spreads
// over 8 banks instead of 16-way conflicting. Broadcast reads are
// same-address (conflict-free regardless); lane-writes stay 2 lanes/bank.
#define PH_BASE(l, P) (((l)*2 + (P)) * 1024)
#define CH_OFF(j, c)  ((j)*128 + (((c) ^ (j)) * 16))

__device__ __forceinline__ float tanh_fast(float v){
    // tanh(x) = 1 - 2/(exp(2x)+1)
    float e = __expf(2.0f * v);
    float r = __builtin_amdgcn_rcpf(e + 1.0f);
    return fmaf(-2.0f, r, 1.0f);
}

// Barrier draining ONLY lgkm: wave-0 x prefetch loads and y stores stay in
// flight across intervals.
__device__ __forceinline__ void barrier_lgkm_only(){
    asm volatile("" ::: "memory");
    __builtin_amdgcn_s_waitcnt(0xc07f);            // lgkmcnt(0), vmcnt/expcnt = max
    __builtin_amdgcn_s_barrier();
    asm volatile("" ::: "memory");
}

// ---------------------------------------------------------------------------
// R7 structure + three changes:
//  1. T2 XOR swizzle on buf (kills the 29.4M-cycle 16-way bank conflict on
//     the MFMA B-frag reads).
//  2. Serial fdot2 accumulation split into 4 chains of depth 8 (+2-level
//     tree): the recurrence is chain-latency-exposed.
//  3. pre[] reads hoisted to registers before the serial loop; y-projection
//     moved to wave 7's MFMA (W_out as A row 0, R5-verified layout).
// Fragment conventions verbatim from the verified R5/R7 kernels:
//   A-frag: lane(g,nn) holds A[row=nn (+16*mt)][k=kt*32+g*8+s]
//   B-frag: lane(g,nn) holds B[k=kt*32+g*8+s][col=nn]  (same k-map -> cancels)
//   C (m89): reg r = C[mt*16+g*4+r][col=nn]
// ---------------------------------------------------------------------------

#define INTERVAL(MM, P, XC, XN) { \
    const int mm = (MM); \
    const bool act = (unsigned)(mm - wv) < (unsigned)NCH; \
    if (wv == 0){ \
        if (mm + 1 < NCH){ \
            _Pragma("unroll") \
            for (int j = 0; j < G; ++j) \
                *(_Float16*)(BB + PH_BASE(0, 1-(P)) + j*128 + (((lane>>3)^j)*16) + (lane&7)*2) = (_Float16)XC[j]; \
        } \
        if (mm + 2 < NCH){ \
            _Pragma("unroll") \
            for (int j = 0; j < G; ++j) \
                XN[j] = x[((size_t)b*TT + (mm+2)*G + j)*HH + lane]; \
        } \
    } \
    if (wv == 7 && mm >= 8){ \
        /* y for chunk mm-8, all 8 slots, via MFMA: D row 0 = W_out . h7 */ \
        GU by0, by1; \
        by0.h = *(const h8*)(BB + PH_BASE(8, P) + CH_OFF(nn&7, g)); \
        by1.h = *(const h8*)(BB + PH_BASE(8, P) + CH_OFF(nn&7, 4+g)); \
        f32x4 ay = {0.f, 0.f, 0.f, 0.f}; \
        ay = __builtin_amdgcn_mfma_f32_16x16x32_f16(woutA[0].v, by0.v, ay, 0, 0, 0); \
        ay = __builtin_amdgcn_mfma_f32_16x16x32_f16(woutA[1].v, by1.v, ay, 0, 0, 0); \
        if (g == 0 && nn < 8) yout[(size_t)b*TT + (mm-8)*G + nn] = ay[0] + bout; \
    } \
    if (act){ \
        /* ---- x-projection GEMM: pre[row][slot] = W_ih . inp[slot] ---- */ \
        GU bx0, bx1; \
        bx0.h = *(const h8*)(BB + PH_BASE(wv, P) + CH_OFF(nn&7, g)); \
        bx1.h = *(const h8*)(BB + PH_BASE(wv, P) + CH_OFF(nn&7, 4+g)); \
        _Pragma("unroll") \
        for (int mt = 0; mt < 4; ++mt){ \
            f32x4 a = {0.f, 0.f, 0.f, 0.f}; \
            a = __builtin_amdgcn_mfma_f32_16x16x32_f16(wihA[mt][0].v, bx0.v, a, 0, 0, 0); \
            a = __builtin_amdgcn_mfma_f32_16x16x32_f16(wihA[mt][1].v, bx1.v, a, 0, 0, 0); \
            if (nn < 8){ \
                _Pragma("unroll") \
                for (int r = 0; r < 4; ++r) \
                    pre[wv][mt*16 + g*4 + r][nn] = a[r]; \
            } \
        } \
        /* hoist the 8 pre reads off the per-step critical path */ \
        float prefj[G]; \
        _Pragma("unroll") \
        for (int j = 0; j < G; ++j) prefj[j] = pre[wv][lane][j]; \
        /* ---- 8 serial steps: W_hh recurrence, 4 fdot chains of depth 8 ---- */ \
        _Pragma("unroll") \
        for (int j = 0; j < G; ++j){ \
            const int jx  = (j == 0) ? (G-1) : (j-1); \
            const int php = (j == 0) ? (P) : (1-(P)); \
            const char* hbase = BB + PH_BASE(wv+1, php); \
            float ach[4]; \
            ach[0] = bsum + prefj[j]; ach[1] = 0.f; ach[2] = 0.f; ach[3] = 0.f; \
            _Pragma("unroll") \
            for (int u = 0; u < 8; ++u){ \
                HU hu; hu.v = *(const h8*)(hbase + jx*128 + ((u^jx)*16)); /* broadcast */ \
                ach[u>>1] = __builtin_amdgcn_fdot2(whh[u*4+0], hu.p[0], ach[u>>1], false); \
                ach[u>>1] = __builtin_amdgcn_fdot2(whh[u*4+1], hu.p[1], ach[u>>1], false); \
                ach[u>>1] = __builtin_amdgcn_fdot2(whh[u*4+2], hu.p[2], ach[u>>1], false); \
                ach[u>>1] = __builtin_amdgcn_fdot2(whh[u*4+3], hu.p[3], ach[u>>1], false); \
            } \
            float hn = tanh_fast((ach[0] + ach[1]) + (ach[2] + ach[3])); \
            *(_Float16*)(BB + PH_BASE(wv+1, 1-(P)) + j*128 + (((lane>>3)^j)*16) + (lane&7)*2) = (_Float16)hn; \
            if (mm - wv == NCH-1 && j == G-1) \
                hout[((size_t)wv*NB + b)*HH + lane] = hn; \
        } \
    } \
    barrier_lgkm_only(); \
}

__global__ void __launch_bounds__(512) rnn_kernel(
    const float* __restrict__ x,        // [B,T,64]
    const float* __restrict__ h_state,  // [8,B,64]
    const float* __restrict__ W_ih0,    // [64,64]
    const float* __restrict__ W_ih,     // [7,64,64]
    const float* __restrict__ W_hh,     // [8,64,64]
    const float* __restrict__ b_ih,     // [8,64]
    const float* __restrict__ b_hh,     // [8,64]
    const float* __restrict__ W_out,    // [1,64]
    const float* __restrict__ b_out,    // [1]
    float* __restrict__ out)            // y[256*2048] ++ h_final[8*256*64]
{
    __shared__ __attribute__((aligned(16))) _Float16 buf[(NL+1)*2*G*HH];  // 18 KB
    __shared__ __attribute__((aligned(16))) float pre[NL][HH][G+1];       // 18.4 KB
    char* BB = (char*)buf;
    const int tid  = threadIdx.x;
    const int wv   = tid >> 6;     // wave id == layer id
    const int lane = tid & 63;
    const int g    = lane >> 4;    // MFMA lane group (k-chunk)
    const int nn   = lane & 15;    // MFMA A-row-in-tile / B,C column
    const size_t b = blockIdx.x;

    // ---- W_hh rows for fdot (lane = row), packed f16 pairs
    h2 whh[32];
    const float2* wh = (const float2*)(W_hh + (size_t)wv*HH*HH);
    #pragma unroll
    for (int i = 0; i < 32; ++i){
        float2 c = wh[lane*32 + i];
        whh[i] = h2{(_Float16)c.x, (_Float16)c.y};
    }
    float bout = b_out[0];
    float bsum = b_ih[wv*HH + lane] + b_hh[wv*HH + lane];

    // ---- W_ih A-fragments for the x-projection MFMA (R5-verified layout)
    GU wihA[4][2];
    const float* Wi = (wv == 0) ? W_ih0 : (W_ih + (size_t)(wv-1)*HH*HH);
    #pragma unroll
    for (int mt = 0; mt < 4; ++mt){
        #pragma unroll
        for (int kt = 0; kt < 2; ++kt){
            const float* pi = Wi + (size_t)(mt*16 + nn)*HH + kt*32 + g*8;
            f32x4 i0 = *(const f32x4*)(pi), i1 = *(const f32x4*)(pi + 4);
            wihA[mt][kt].p[0] = __builtin_amdgcn_cvt_pkrtz(i0[0], i0[1]);
            wihA[mt][kt].p[1] = __builtin_amdgcn_cvt_pkrtz(i0[2], i0[3]);
            wihA[mt][kt].p[2] = __builtin_amdgcn_cvt_pkrtz(i1[0], i1[1]);
            wihA[mt][kt].p[3] = __builtin_amdgcn_cvt_pkrtz(i1[2], i1[3]);
        }
    }

    // ---- wave 7: W_out as A row 0 (rows 1..15 zero) for the y MFMA
    GU woutA[2];
    if (wv == 7){
        #pragma unroll
        for (int kt = 0; kt < 2; ++kt)
            #pragma unroll
            for (int q = 0; q < 4; ++q){
                float a0 = (nn == 0) ? W_out[kt*32 + g*8 + q*2]     : 0.f;
                float a1 = (nn == 0) ? W_out[kt*32 + g*8 + q*2 + 1] : 0.f;
                woutA[kt].p[q] = __builtin_amdgcn_cvt_pkrtz(a0, a1);
            }
    }

    // ---- zero queues, place initial state + first x chunk (swizzled writes)
    for (int i = tid; i < (NL+1)*2*G*HH; i += 512) buf[i] = (_Float16)0.f;
    __syncthreads();
    // wave l's first interval is m=l (read phase 1-(l&1)); j=0 reads slot G-1
    *(_Float16*)(BB + PH_BASE(wv+1, 1-(wv&1)) + (G-1)*128 + (((lane>>3)^(G-1))*16) + (lane&7)*2)
        = (_Float16)h_state[((size_t)wv*NB + b)*HH + lane];
    float xa[G], xb[G];
    if (wv == 0){
        #pragma unroll
        for (int j = 0; j < G; ++j){
            // x chunk 0 (t=0..7), read at m=0 (phase 1)
            *(_Float16*)(BB + PH_BASE(0, 1) + j*128 + (((lane>>3)^j)*16) + (lane&7)*2)
                = (_Float16)x[((size_t)b*TT + j)*HH + lane];
            xa[j] = x[((size_t)b*TT + G + j)*HH + lane];   // chunk 1, staged during m=0
        }
    }
    __syncthreads();

    float* yout = out;                    // [B*T]
    float* hout = out + (size_t)NB*TT;    // [8,B,64]

    for (int m2 = 0; m2 < NI; m2 += 2){
        INTERVAL(m2,     1, xa, xb)
        INTERVAL(m2 + 1, 0, xb, xa)
    }
    // no epilogue: interval NI-1 emits y for the final chunk (all 8 slots)
}

extern "C" void kernel_launch(void* const* d_in, const int* in_sizes, int n_in,
                              void* d_out, int out_size, void* d_ws, size_t ws_size,
                              hipStream_t stream) {
    (void)in_sizes; (void)n_in; (void)d_ws; (void)ws_size; (void)out_size;
    const float* x       = (const float*)d_in[0];
    const float* h_state = (const float*)d_in[1];
    const float* W_ih0   = (const float*)d_in[2];
    const float* W_ih    = (const float*)d_in[3];
    const float* W_hh    = (const float*)d_in[4];
    const float* b_ih    = (const float*)d_in[5];
    const float* b_hh    = (const float*)d_in[6];
    const float* W_out   = (const float*)d_in[7];
    const float* b_out   = (const float*)d_in[8];
    float* out = (float*)d_out;

    rnn_kernel<<<dim3(NB), dim3(512), 0, stream>>>(
        x, h_state, W_ih0, W_ih, W_hh, b_ih, b_hh, W_out, b_out, out);
}

// Round 9
// 519.772 us; speedup vs baseline: 3.2848x; 1.2022x over previous
//
#include <hip/hip_runtime.h>

typedef _Float16 h2 __attribute__((ext_vector_type(2)));
typedef _Float16 h8 __attribute__((ext_vector_type(8)));
typedef __fp16   g2 __attribute__((ext_vector_type(2)));
typedef __fp16   g8 __attribute__((ext_vector_type(8)));
typedef float    f32x4 __attribute__((ext_vector_type(4)));

#define TT 2048
#define HH 64
#define NL 8
#define NB 256
#define G  8            // timesteps per barrier interval
#define NCH (TT/G)      // 256 chunks per layer
#define NI  (NCH + NL)  // 264 intervals

union GU { g8 v; g2 p[4]; h8 h; };   // bitcast LDS (_Float16) <-> MFMA (__fp16)

// buf byte layout: boundary l (0..8), phase P (0..1), slot j (0..7), 64 f16.
// Within a slot row (128 B) the 16-B chunk c is stored at index c^j.
#define PH_BASE(l, P) (((l)*2 + (P)) * 1024)
#define CH_OFF(j, c)  ((j)*128 + (((c) ^ (j)) * 16))

__device__ __forceinline__ float tanh_fast(float v){
    float e = __expf(2.0f * v);
    float r = __builtin_amdgcn_rcpf(e + 1.0f);
    return fmaf(-2.0f, r, 1.0f);
}

__device__ __forceinline__ void barrier_lgkm_only(){
    asm volatile("" ::: "memory");
    __builtin_amdgcn_s_waitcnt(0xc07f);            // lgkmcnt(0), vmcnt/expcnt = max
    __builtin_amdgcn_s_barrier();
    asm volatile("" ::: "memory");
}

// ---------------------------------------------------------------------------
// Transposed-MFMA recurrence (replaces all fdot2):
//   A-frag: lane(g,nn) holds A[row=nn][k=kt*32+g*8+s]   (R5/R8-verified)
//   B-frag: lane(g,nn) holds B[k=kt*32+g*8+s][col=nn]   (same k-map -> cancels)
//   C/D (m89): reg r = C[m=g*4+r][col=nn]
// x-proj:  A = inp slots (rows=slots), B = W_ih rows-as-cols
//          -> D[slot=g*4+r][w-row=t*16+nn] = pre  (spill slots 0..7, g<2)
// h-step:  A rows ALL = h_j (read indep of nn), B = W_hh rows-as-cols
//          -> D[m][c] m-independent: reg0 = pre-init + (Whh h)[t*16+nn]
//          lane keeps t==g  =>  lane l holds h_new[l]; 1 tanh/lane.
// y (wv7): A = h7 slots, B cols all = W_out -> reg r = y[slot g*4+r]
// ---------------------------------------------------------------------------

#define INTERVAL(MM, P, XC, XN) { \
    const int mm = (MM); \
    const bool act = (unsigned)(mm - wv) < (unsigned)NCH; \
    if (wv == 0){ \
        if (mm + 1 < NCH){ \
            _Pragma("unroll") \
            for (int j = 0; j < G; ++j) \
                *(_Float16*)(BB + PH_BASE(0, 1-(P)) + j*128 + (((lane>>3)^j)*16) + (lane&7)*2) = (_Float16)XC[j]; \
        } \
        if (mm + 2 < NCH){ \
            _Pragma("unroll") \
            for (int j = 0; j < G; ++j) \
                XN[j] = x[((size_t)b*TT + (mm+2)*G + j)*HH + lane]; \
        } \
    } \
    if (wv == 7 && mm >= 8){ \
        GU ha0, ha1; \
        ha0.h = *(const h8*)(BB + PH_BASE(8, P) + CH_OFF(nn&7, g)); \
        ha1.h = *(const h8*)(BB + PH_BASE(8, P) + CH_OFF(nn&7, 4+g)); \
        f32x4 ay = {0.f, 0.f, 0.f, 0.f}; \
        ay = __builtin_amdgcn_mfma_f32_16x16x32_f16(ha0.v, woutB[0].v, ay, 0, 0, 0); \
        ay = __builtin_amdgcn_mfma_f32_16x16x32_f16(ha1.v, woutB[1].v, ay, 0, 0, 0); \
        if (nn == 0 && g < 2){ \
            f32x4 st; \
            st[0] = ay[0] + bout; st[1] = ay[1] + bout; \
            st[2] = ay[2] + bout; st[3] = ay[3] + bout; \
            *(f32x4*)(yout + (size_t)b*TT + (size_t)(mm-8)*G + g*4) = st; \
        } \
    } \
    if (act){ \
        /* ---- x-projection (swapped operands): D[slot][w-row] ---- */ \
        GU bx0, bx1; \
        bx0.h = *(const h8*)(BB + PH_BASE(wv, P) + CH_OFF(nn&7, g)); \
        bx1.h = *(const h8*)(BB + PH_BASE(wv, P) + CH_OFF(nn&7, 4+g)); \
        f32x4 xd0 = {bs[0],bs[0],bs[0],bs[0]}, xd1 = {bs[1],bs[1],bs[1],bs[1]}; \
        f32x4 xd2 = {bs[2],bs[2],bs[2],bs[2]}, xd3 = {bs[3],bs[3],bs[3],bs[3]}; \
        xd0 = __builtin_amdgcn_mfma_f32_16x16x32_f16(bx0.v, wihA[0][0].v, xd0, 0, 0, 0); \
        xd0 = __builtin_amdgcn_mfma_f32_16x16x32_f16(bx1.v, wihA[0][1].v, xd0, 0, 0, 0); \
        xd1 = __builtin_amdgcn_mfma_f32_16x16x32_f16(bx0.v, wihA[1][0].v, xd1, 0, 0, 0); \
        xd1 = __builtin_amdgcn_mfma_f32_16x16x32_f16(bx1.v, wihA[1][1].v, xd1, 0, 0, 0); \
        xd2 = __builtin_amdgcn_mfma_f32_16x16x32_f16(bx0.v, wihA[2][0].v, xd2, 0, 0, 0); \
        xd2 = __builtin_amdgcn_mfma_f32_16x16x32_f16(bx1.v, wihA[2][1].v, xd2, 0, 0, 0); \
        xd3 = __builtin_amdgcn_mfma_f32_16x16x32_f16(bx0.v, wihA[3][0].v, xd3, 0, 0, 0); \
        xd3 = __builtin_amdgcn_mfma_f32_16x16x32_f16(bx1.v, wihA[3][1].v, xd3, 0, 0, 0); \
        if (g < 2){ \
            _Pragma("unroll") \
            for (int r = 0; r < 4; ++r){ \
                preT[wv][g*4+r][nn][0] = xd0[r]; \
                preT[wv][g*4+r][nn][1] = xd1[r]; \
                preT[wv][g*4+r][nn][2] = xd2[r]; \
                preT[wv][g*4+r][nn][3] = xd3[r]; \
            } \
        } \
        /* ---- 8 serial steps: h-matvec on MFMA ---- */ \
        _Pragma("unroll") \
        for (int j = 0; j < G; ++j){ \
            const int jx  = (j == 0) ? (G-1) : (j-1); \
            const int php = (j == 0) ? (P) : (1-(P)); \
            GU hA0, hA1; \
            hA0.h = *(const h8*)(BB + PH_BASE(wv+1, php) + CH_OFF(jx, g)); \
            hA1.h = *(const h8*)(BB + PH_BASE(wv+1, php) + CH_OFF(jx, 4+g)); \
            const f32x4 ptv = *(const f32x4*)(&preT[wv][j][nn][0]); \
            f32x4 a0 = {ptv[0], 0.f, 0.f, 0.f}; \
            f32x4 a1 = {ptv[1], 0.f, 0.f, 0.f}; \
            f32x4 a2 = {ptv[2], 0.f, 0.f, 0.f}; \
            f32x4 a3 = {ptv[3], 0.f, 0.f, 0.f}; \
            a0 = __builtin_amdgcn_mfma_f32_16x16x32_f16(hA0.v, whhB[0][0].v, a0, 0, 0, 0); \
            a0 = __builtin_amdgcn_mfma_f32_16x16x32_f16(hA1.v, whhB[0][1].v, a0, 0, 0, 0); \
            a1 = __builtin_amdgcn_mfma_f32_16x16x32_f16(hA0.v, whhB[1][0].v, a1, 0, 0, 0); \
            a1 = __builtin_amdgcn_mfma_f32_16x16x32_f16(hA1.v, whhB[1][1].v, a1, 0, 0, 0); \
            a2 = __builtin_amdgcn_mfma_f32_16x16x32_f16(hA0.v, whhB[2][0].v, a2, 0, 0, 0); \
            a2 = __builtin_amdgcn_mfma_f32_16x16x32_f16(hA1.v, whhB[2][1].v, a2, 0, 0, 0); \
            a3 = __builtin_amdgcn_mfma_f32_16x16x32_f16(hA0.v, whhB[3][0].v, a3, 0, 0, 0); \
            a3 = __builtin_amdgcn_mfma_f32_16x16x32_f16(hA1.v, whhB[3][1].v, a3, 0, 0, 0); \
            const float pa = (g & 2) ? ((g & 1) ? a3[0] : a2[0]) \
                                     : ((g & 1) ? a1[0] : a0[0]); \
            const float hn = tanh_fast(pa); \
            *(_Float16*)(BB + PH_BASE(wv+1, 1-(P)) + j*128 + (((lane>>3)^j)*16) + (lane&7)*2) = (_Float16)hn; \
            if (mm - wv == NCH-1 && j == G-1) \
                hout[((size_t)wv*NB + b)*HH + lane] = hn; \
        } \
    } \
    barrier_lgkm_only(); \
}

__global__ void __launch_bounds__(512) rnn_kernel(
    const float* __restrict__ x,        // [B,T,64]
    const float* __restrict__ h_state,  // [8,B,64]
    const float* __restrict__ W_ih0,    // [64,64]
    const float* __restrict__ W_ih,     // [7,64,64]
    const float* __restrict__ W_hh,     // [8,64,64]
    const float* __restrict__ b_ih,     // [8,64]
    const float* __restrict__ b_hh,     // [8,64]
    const float* __restrict__ W_out,    // [1,64]
    const float* __restrict__ b_out,    // [1]
    float* __restrict__ out)            // y[256*2048] ++ h_final[8*256*64]
{
    __shared__ __attribute__((aligned(16))) _Float16 buf[(NL+1)*2*G*HH];  // 18 KB
    __shared__ __attribute__((aligned(16))) float preT[NL][G][16][4];     // 16 KB
    char* BB = (char*)buf;
    const int tid  = threadIdx.x;
    const int wv   = tid >> 6;     // wave id == layer id
    const int lane = tid & 63;
    const int g    = lane >> 4;    // MFMA lane group (k-chunk)
    const int nn   = lane & 15;    // MFMA row-in-tile / column
    const size_t b = blockIdx.x;

    // ---- W_ih / W_hh fragments: lane (g,nn) holds W[t*16+nn][kt*32+g*8 + 0..7]
    GU wihA[4][2], whhB[4][2];
    const float* Wi = (wv == 0) ? W_ih0 : (W_ih + (size_t)(wv-1)*HH*HH);
    const float* Wh = W_hh + (size_t)wv*HH*HH;
    #pragma unroll
    for (int t = 0; t < 4; ++t){
        #pragma unroll
        for (int kt = 0; kt < 2; ++kt){
            const float* pi = Wi + (size_t)(t*16 + nn)*HH + kt*32 + g*8;
            const float* ph = Wh + (size_t)(t*16 + nn)*HH + kt*32 + g*8;
            f32x4 i0 = *(const f32x4*)(pi), i1 = *(const f32x4*)(pi + 4);
            f32x4 h0 = *(const f32x4*)(ph), h1 = *(const f32x4*)(ph + 4);
            wihA[t][kt].p[0] = __builtin_amdgcn_cvt_pkrtz(i0[0], i0[1]);
            wihA[t][kt].p[1] = __builtin_amdgcn_cvt_pkrtz(i0[2], i0[3]);
            wihA[t][kt].p[2] = __builtin_amdgcn_cvt_pkrtz(i1[0], i1[1]);
            wihA[t][kt].p[3] = __builtin_amdgcn_cvt_pkrtz(i1[2], i1[3]);
            whhB[t][kt].p[0] = __builtin_amdgcn_cvt_pkrtz(h0[0], h0[1]);
            whhB[t][kt].p[1] = __builtin_amdgcn_cvt_pkrtz(h0[2], h0[3]);
            whhB[t][kt].p[2] = __builtin_amdgcn_cvt_pkrtz(h1[0], h1[1]);
            whhB[t][kt].p[3] = __builtin_amdgcn_cvt_pkrtz(h1[2], h1[3]);
        }
    }
    // ---- biases per w-row tile: bs[t] for row t*16+nn
    float bs[4];
    #pragma unroll
    for (int t = 0; t < 4; ++t)
        bs[t] = b_ih[wv*HH + t*16 + nn] + b_hh[wv*HH + t*16 + nn];
    float bout = b_out[0];

    // ---- wave 7: W_out replicated across columns (B[k][c] = W_out[k] for all c)
    GU woutB[2];
    if (wv == 7){
        #pragma unroll
        for (int kt = 0; kt < 2; ++kt)
            #pragma unroll
            for (int q = 0; q < 4; ++q)
                woutB[kt].p[q] = __builtin_amdgcn_cvt_pkrtz(
                    W_out[kt*32 + g*8 + q*2], W_out[kt*32 + g*8 + q*2 + 1]);
    }

    // ---- zero queues, place initial state + first x chunk (swizzled writes)
    for (int i = tid; i < (NL+1)*2*G*HH; i += 512) buf[i] = (_Float16)0.f;
    __syncthreads();
    *(_Float16*)(BB + PH_BASE(wv+1, 1-(wv&1)) + (G-1)*128 + (((lane>>3)^(G-1))*16) + (lane&7)*2)
        = (_Float16)h_state[((size_t)wv*NB + b)*HH + lane];
    float xa[G], xb[G];
    if (wv == 0){
        #pragma unroll
        for (int j = 0; j < G; ++j){
            *(_Float16*)(BB + PH_BASE(0, 1) + j*128 + (((lane>>3)^j)*16) + (lane&7)*2)
                = (_Float16)x[((size_t)b*TT + j)*HH + lane];
            xa[j] = x[((size_t)b*TT + G + j)*HH + lane];
        }
    }
    __syncthreads();

    float* yout = out;                    // [B*T]
    float* hout = out + (size_t)NB*TT;    // [8,B,64]

    for (int m2 = 0; m2 < NI; m2 += 2){
        INTERVAL(m2,     1, xa, xb)
        INTERVAL(m2 + 1, 0, xb, xa)
    }
    // no epilogue: interval NI-1 emits y for the final chunk (all 8 slots)
}

extern "C" void kernel_launch(void* const* d_in, const int* in_sizes, int n_in,
                              void* d_out, int out_size, void* d_ws, size_t ws_size,
                              hipStream_t stream) {
    (void)in_sizes; (void)n_in; (void)d_ws; (void)ws_size; (void)out_size;
    const float* x       = (const float*)d_in[0];
    const float* h_state = (const float*)d_in[1];
    const float* W_ih0   = (const float*)d_in[2];
    const float* W_ih    = (const float*)d_in[3];
    const float* W_hh    = (const float*)d_in[4];
    const float* b_ih    = (const float*)d_in[5];
    const float* b_hh    = (const float*)d_in[6];
    const float* W_out   = (const float*)d_in[7];
    const float* b_out   = (const float*)d_in[8];
    float* out = (float*)d_out;

    rnn_kernel<<<dim3(NB), dim3(512), 0, stream>>>(
        x, h_state, W_ih0, W_ih, W_hh, b_ih, b_hh, W_out, b_out, out);
}

// Round 10
// 518.859 us; speedup vs baseline: 3.2906x; 1.0018x over previous
//
#include <hip/hip_runtime.h>

typedef _Float16 h2 __attribute__((ext_vector_type(2)));
typedef _Float16 h8 __attribute__((ext_vector_type(8)));
typedef __fp16   g2 __attribute__((ext_vector_type(2)));
typedef __fp16   g8 __attribute__((ext_vector_type(8)));
typedef float    f32x4 __attribute__((ext_vector_type(4)));

#define TT 2048
#define HH 64
#define NL 8
#define NB 256
#define G  8            // timesteps per barrier interval
#define NCH (TT/G)      // 256 chunks per layer
#define NI  (NCH + NL)  // 264 intervals

union GU { g8 v; g2 p[4]; h8 h; };   // bitcast LDS (_Float16) <-> MFMA (__fp16)

// buf byte layout: boundary l (0..8), phase P (0..1), slot j (0..7), 64 f16.
// Within a slot row (128 B) the 16-B chunk c is stored at index c^j.
#define PH_BASE(l, P) (((l)*2 + (P)) * 1024)
#define CH_OFF(j, c)  ((j)*128 + (((c) ^ (j)) * 16))

__device__ __forceinline__ float tanh_fast(float v){
    float e = __expf(2.0f * v);
    float r = __builtin_amdgcn_rcpf(e + 1.0f);
    return fmaf(-2.0f, r, 1.0f);
}

__device__ __forceinline__ void barrier_lgkm_only(){
    asm volatile("" ::: "memory");
    __builtin_amdgcn_s_waitcnt(0xc07f);            // lgkmcnt(0), vmcnt/expcnt = max
    __builtin_amdgcn_s_barrier();
    asm volatile("" ::: "memory");
}

// ---------------------------------------------------------------------------
// R9 transposed-MFMA structure + serial-chain trims:
//  - kt0/kt1 MFMAs independent (C=0), summed after -> dep chain is 1 MFMA.
//  - pre+bias enters as a scalar add after the select (only ptv[g] was ever
//    used); preT readback is a batched b32 per step, off the MFMA path.
//  - j=0 hA fragments prefetched across the barrier (self-written slot 7).
// Fragment conventions (R5/R8/R9-verified):
//   A-frag: lane(g,nn) holds A[row=nn][k=kt*32+g*8+s]
//   B-frag: lane(g,nn) holds B[k=kt*32+g*8+s][col=nn]  (same k-map -> cancels)
//   C/D (m89): reg r = C[m=g*4+r][col=nn]
// ---------------------------------------------------------------------------

#define INTERVAL(MM, P, XC, XN) { \
    const int mm = (MM); \
    const bool act = (unsigned)(mm - wv) < (unsigned)NCH; \
    if (wv == 0){ \
        if (mm + 1 < NCH){ \
            _Pragma("unroll") \
            for (int j = 0; j < G; ++j) \
                *(_Float16*)(BB + PH_BASE(0, 1-(P)) + j*128 + (((lane>>3)^j)*16) + (lane&7)*2) = (_Float16)XC[j]; \
        } \
        if (mm + 2 < NCH){ \
            _Pragma("unroll") \
            for (int j = 0; j < G; ++j) \
                XN[j] = x[((size_t)b*TT + (mm+2)*G + j)*HH + lane]; \
        } \
    } \
    if (wv == 7 && mm >= 8){ \
        GU ha0, ha1; \
        ha0.h = *(const h8*)(BB + PH_BASE(8, P) + CH_OFF(nn&7, g)); \
        ha1.h = *(const h8*)(BB + PH_BASE(8, P) + CH_OFF(nn&7, 4+g)); \
        f32x4 ay = {0.f, 0.f, 0.f, 0.f}; \
        ay = __builtin_amdgcn_mfma_f32_16x16x32_f16(ha0.v, woutB[0].v, ay, 0, 0, 0); \
        ay = __builtin_amdgcn_mfma_f32_16x16x32_f16(ha1.v, woutB[1].v, ay, 0, 0, 0); \
        if (nn == 0 && g < 2){ \
            f32x4 st; \
            st[0] = ay[0] + bout; st[1] = ay[1] + bout; \
            st[2] = ay[2] + bout; st[3] = ay[3] + bout; \
            *(f32x4*)(yout + (size_t)b*TT + (size_t)(mm-8)*G + g*4) = st; \
        } \
    } \
    if (act){ \
        /* ---- x-projection (swapped operands): D[slot][w-row], bias in C ---- */ \
        GU bx0, bx1; \
        bx0.h = *(const h8*)(BB + PH_BASE(wv, P) + CH_OFF(nn&7, g)); \
        bx1.h = *(const h8*)(BB + PH_BASE(wv, P) + CH_OFF(nn&7, 4+g)); \
        f32x4 xd0 = {bs[0],bs[0],bs[0],bs[0]}, xd1 = {bs[1],bs[1],bs[1],bs[1]}; \
        f32x4 xd2 = {bs[2],bs[2],bs[2],bs[2]}, xd3 = {bs[3],bs[3],bs[3],bs[3]}; \
        xd0 = __builtin_amdgcn_mfma_f32_16x16x32_f16(bx0.v, wihA[0][0].v, xd0, 0, 0, 0); \
        xd0 = __builtin_amdgcn_mfma_f32_16x16x32_f16(bx1.v, wihA[0][1].v, xd0, 0, 0, 0); \
        xd1 = __builtin_amdgcn_mfma_f32_16x16x32_f16(bx0.v, wihA[1][0].v, xd1, 0, 0, 0); \
        xd1 = __builtin_amdgcn_mfma_f32_16x16x32_f16(bx1.v, wihA[1][1].v, xd1, 0, 0, 0); \
        xd2 = __builtin_amdgcn_mfma_f32_16x16x32_f16(bx0.v, wihA[2][0].v, xd2, 0, 0, 0); \
        xd2 = __builtin_amdgcn_mfma_f32_16x16x32_f16(bx1.v, wihA[2][1].v, xd2, 0, 0, 0); \
        xd3 = __builtin_amdgcn_mfma_f32_16x16x32_f16(bx0.v, wihA[3][0].v, xd3, 0, 0, 0); \
        xd3 = __builtin_amdgcn_mfma_f32_16x16x32_f16(bx1.v, wihA[3][1].v, xd3, 0, 0, 0); \
        if (g < 2){ \
            _Pragma("unroll") \
            for (int r = 0; r < 4; ++r){ \
                preT[wv][g*4+r][nn][0] = xd0[r]; \
                preT[wv][g*4+r][nn][1] = xd1[r]; \
                preT[wv][g*4+r][nn][2] = xd2[r]; \
                preT[wv][g*4+r][nn][3] = xd3[r]; \
            } \
        } \
        /* batched b32 readback: only [j][nn][g] is ever used by this lane */ \
        float pr[G]; \
        _Pragma("unroll") \
        for (int j = 0; j < G; ++j) pr[j] = preTf[((wv*G + j)*16 + nn)*4 + g]; \
        /* ---- 8 serial steps: h-matvec, dep chain = 1 MFMA ---- */ \
        _Pragma("unroll") \
        for (int j = 0; j < G; ++j){ \
            GU hA0, hA1; \
            if (j == 0){ hA0 = hp0; hA1 = hp1; } \
            else { \
                hA0.h = *(const h8*)(BB + PH_BASE(wv+1, 1-(P)) + CH_OFF(j-1, g)); \
                hA1.h = *(const h8*)(BB + PH_BASE(wv+1, 1-(P)) + CH_OFF(j-1, 4+g)); \
            } \
            const f32x4 zz = {0.f, 0.f, 0.f, 0.f}; \
            f32x4 a00 = __builtin_amdgcn_mfma_f32_16x16x32_f16(hA0.v, whhB[0][0].v, zz, 0, 0, 0); \
            f32x4 a01 = __builtin_amdgcn_mfma_f32_16x16x32_f16(hA1.v, whhB[0][1].v, zz, 0, 0, 0); \
            f32x4 a10 = __builtin_amdgcn_mfma_f32_16x16x32_f16(hA0.v, whhB[1][0].v, zz, 0, 0, 0); \
            f32x4 a11 = __builtin_amdgcn_mfma_f32_16x16x32_f16(hA1.v, whhB[1][1].v, zz, 0, 0, 0); \
            f32x4 a20 = __builtin_amdgcn_mfma_f32_16x16x32_f16(hA0.v, whhB[2][0].v, zz, 0, 0, 0); \
            f32x4 a21 = __builtin_amdgcn_mfma_f32_16x16x32_f16(hA1.v, whhB[2][1].v, zz, 0, 0, 0); \
            f32x4 a30 = __builtin_amdgcn_mfma_f32_16x16x32_f16(hA0.v, whhB[3][0].v, zz, 0, 0, 0); \
            f32x4 a31 = __builtin_amdgcn_mfma_f32_16x16x32_f16(hA1.v, whhB[3][1].v, zz, 0, 0, 0); \
            const float s0 = a00[0] + a01[0], s1 = a10[0] + a11[0]; \
            const float s2 = a20[0] + a21[0], s3 = a30[0] + a31[0]; \
            const float pa = (g & 2) ? ((g & 1) ? s3 : s2) : ((g & 1) ? s1 : s0); \
            const float hn = tanh_fast(pa + pr[j]); \
            *(_Float16*)(BB + PH_BASE(wv+1, 1-(P)) + j*128 + (((lane>>3)^j)*16) + (lane&7)*2) = (_Float16)hn; \
            if (j == G-1){ \
                /* prefetch next interval's j=0 A-frags (self-written slot 7) */ \
                hp0.h = *(const h8*)(BB + PH_BASE(wv+1, 1-(P)) + CH_OFF(G-1, g)); \
                hp1.h = *(const h8*)(BB + PH_BASE(wv+1, 1-(P)) + CH_OFF(G-1, 4+g)); \
            } \
            if (mm - wv == NCH-1 && j == G-1) \
                hout[((size_t)wv*NB + b)*HH + lane] = hn; \
        } \
    } \
    barrier_lgkm_only(); \
}

__global__ void __launch_bounds__(512) rnn_kernel(
    const float* __restrict__ x,        // [B,T,64]
    const float* __restrict__ h_state,  // [8,B,64]
    const float* __restrict__ W_ih0,    // [64,64]
    const float* __restrict__ W_ih,     // [7,64,64]
    const float* __restrict__ W_hh,     // [8,64,64]
    const float* __restrict__ b_ih,     // [8,64]
    const float* __restrict__ b_hh,     // [8,64]
    const float* __restrict__ W_out,    // [1,64]
    const float* __restrict__ b_out,    // [1]
    float* __restrict__ out)            // y[256*2048] ++ h_final[8*256*64]
{
    __shared__ __attribute__((aligned(16))) _Float16 buf[(NL+1)*2*G*HH];  // 18 KB
    __shared__ __attribute__((aligned(16))) float preT[NL][G][16][4];     // 16 KB
    char* BB = (char*)buf;
    float* preTf = (float*)preT;
    const int tid  = threadIdx.x;
    const int wv   = tid >> 6;     // wave id == layer id
    const int lane = tid & 63;
    const int g    = lane >> 4;    // MFMA lane group (k-chunk)
    const int nn   = lane & 15;    // MFMA row-in-tile / column
    const size_t b = blockIdx.x;

    // ---- W_ih / W_hh fragments: lane (g,nn) holds W[t*16+nn][kt*32+g*8 + 0..7]
    GU wihA[4][2], whhB[4][2];
    const float* Wi = (wv == 0) ? W_ih0 : (W_ih + (size_t)(wv-1)*HH*HH);
    const float* Wh = W_hh + (size_t)wv*HH*HH;
    #pragma unroll
    for (int t = 0; t < 4; ++t){
        #pragma unroll
        for (int kt = 0; kt < 2; ++kt){
            const float* pi = Wi + (size_t)(t*16 + nn)*HH + kt*32 + g*8;
            const float* ph = Wh + (size_t)(t*16 + nn)*HH + kt*32 + g*8;
            f32x4 i0 = *(const f32x4*)(pi), i1 = *(const f32x4*)(pi + 4);
            f32x4 h0 = *(const f32x4*)(ph), h1 = *(const f32x4*)(ph + 4);
            wihA[t][kt].p[0] = __builtin_amdgcn_cvt_pkrtz(i0[0], i0[1]);
            wihA[t][kt].p[1] = __builtin_amdgcn_cvt_pkrtz(i0[2], i0[3]);
            wihA[t][kt].p[2] = __builtin_amdgcn_cvt_pkrtz(i1[0], i1[1]);
            wihA[t][kt].p[3] = __builtin_amdgcn_cvt_pkrtz(i1[2], i1[3]);
            whhB[t][kt].p[0] = __builtin_amdgcn_cvt_pkrtz(h0[0], h0[1]);
            whhB[t][kt].p[1] = __builtin_amdgcn_cvt_pkrtz(h0[2], h0[3]);
            whhB[t][kt].p[2] = __builtin_amdgcn_cvt_pkrtz(h1[0], h1[1]);
            whhB[t][kt].p[3] = __builtin_amdgcn_cvt_pkrtz(h1[2], h1[3]);
        }
    }
    // ---- biases per w-row tile: bs[t] for row t*16+nn (flows through preT)
    float bs[4];
    #pragma unroll
    for (int t = 0; t < 4; ++t)
        bs[t] = b_ih[wv*HH + t*16 + nn] + b_hh[wv*HH + t*16 + nn];
    float bout = b_out[0];

    // ---- wave 7: W_out replicated across columns (B[k][c] = W_out[k] for all c)
    GU woutB[2];
    if (wv == 7){
        #pragma unroll
        for (int kt = 0; kt < 2; ++kt)
            #pragma unroll
            for (int q = 0; q < 4; ++q)
                woutB[kt].p[q] = __builtin_amdgcn_cvt_pkrtz(
                    W_out[kt*32 + g*8 + q*2], W_out[kt*32 + g*8 + q*2 + 1]);
    }

    // ---- zero queues, place initial state + first x chunk (swizzled writes)
    for (int i = tid; i < (NL+1)*2*G*HH; i += 512) buf[i] = (_Float16)0.f;
    __syncthreads();
    *(_Float16*)(BB + PH_BASE(wv+1, 1-(wv&1)) + (G-1)*128 + (((lane>>3)^(G-1))*16) + (lane&7)*2)
        = (_Float16)h_state[((size_t)wv*NB + b)*HH + lane];
    float xa[G], xb[G];
    if (wv == 0){
        #pragma unroll
        for (int j = 0; j < G; ++j){
            *(_Float16*)(BB + PH_BASE(0, 1) + j*128 + (((lane>>3)^j)*16) + (lane&7)*2)
                = (_Float16)x[((size_t)b*TT + j)*HH + lane];
            xa[j] = x[((size_t)b*TT + G + j)*HH + lane];
        }
    }
    __syncthreads();

    // ---- prologue prefetch: j=0 A-frags for this wave's first active interval
    // (slot G-1 of phase 1-(wv&1) = the h_state we just placed; self-written,
    //  same-wave DS order guarantees the data)
    GU hp0, hp1;
    hp0.h = *(const h8*)(BB + PH_BASE(wv+1, 1-(wv&1)) + CH_OFF(G-1, g));
    hp1.h = *(const h8*)(BB + PH_BASE(wv+1, 1-(wv&1)) + CH_OFF(G-1, 4+g));

    float* yout = out;                    // [B*T]
    float* hout = out + (size_t)NB*TT;    // [8,B,64]

    for (int m2 = 0; m2 < NI; m2 += 2){
        INTERVAL(m2,     1, xa, xb)
        INTERVAL(m2 + 1, 0, xb, xa)
    }
    // no epilogue: interval NI-1 emits y for the final chunk (all 8 slots)
}

extern "C" void kernel_launch(void* const* d_in, const int* in_sizes, int n_in,
                              void* d_out, int out_size, void* d_ws, size_t ws_size,
                              hipStream_t stream) {
    (void)in_sizes; (void)n_in; (void)d_ws; (void)ws_size; (void)out_size;
    const float* x       = (const float*)d_in[0];
    const float* h_state = (const float*)d_in[1];
    const float* W_ih0   = (const float*)d_in[2];
    const float* W_ih    = (const float*)d_in[3];
    const float* W_hh    = (const float*)d_in[4];
    const float* b_ih    = (const float*)d_in[5];
    const float* b_hh    = (const float*)d_in[6];
    const float* W_out   = (const float*)d_in[7];
    const float* b_out   = (const float*)d_in[8];
    float* out = (float*)d_out;

    rnn_kernel<<<dim3(NB), dim3(512), 0, stream>>>(
        x, h_state, W_ih0, W_ih, W_hh, b_ih, b_hh, W_out, b_out, out);
}

// Round 11
// 487.564 us; speedup vs baseline: 3.5018x; 1.0642x over previous
//
#include <hip/hip_runtime.h>

typedef _Float16 h2 __attribute__((ext_vector_type(2)));
typedef _Float16 h8 __attribute__((ext_vector_type(8)));
typedef __fp16   g2 __attribute__((ext_vector_type(2)));
typedef __fp16   g8 __attribute__((ext_vector_type(8)));
typedef float    f32x4 __attribute__((ext_vector_type(4)));

#define TT 2048
#define HH 64
#define NL 8
#define NB 256
#define G  16           // timesteps per barrier interval (was 8)
#define NCH (TT/G)      // 128 chunks per layer
#define NI  (NCH + NL)  // 136 intervals

#define PRP 20          // preT row pad (words): 16B-aligned, spreads banks

union GU { g8 v; g2 p[4]; h8 h; };   // bitcast LDS (_Float16) <-> MFMA (__fp16)

// buf byte layout: boundary l (0..8), phase P (0..1), slot j (0..15), 64 f16.
// Within a slot row (128 B) the 16-B chunk c is stored at index c^(j&7).
#define PH_BASE(l, P) (((l)*2 + (P)) * 2048)
#define CH_OFF(j, c)  ((j)*128 + ((((c) ^ ((j)&7))) * 16))

__device__ __forceinline__ float tanh_fast(float v){
    float e = __expf(2.0f * v);
    float r = __builtin_amdgcn_rcpf(e + 1.0f);
    return fmaf(-2.0f, r, 1.0f);
}

__device__ __forceinline__ void barrier_lgkm_only(){
    asm volatile("" ::: "memory");
    __builtin_amdgcn_s_waitcnt(0xc07f);            // lgkmcnt(0), vmcnt/expcnt = max
    __builtin_amdgcn_s_barrier();
    asm volatile("" ::: "memory");
}

// ---------------------------------------------------------------------------
// R10 transposed-MFMA structure with G=16 (interval-overhead amortization):
//  - barriers 264 -> 136; serial heads (drain + bx read + spill roundtrip)
//    and fill/drain waste halve.
//  - x-proj m-dim now fully used: 8 MFMAs cover 16 slots (was 8).
//  - preT: [nn][t-row][16 slots + pad] f32; spill 4xb128, readback 4xb128.
// Fragment conventions (R5/R8/R9-verified):
//   A-frag: lane(g,nn) holds A[row=nn][k=kt*32+g*8+s]
//   B-frag: lane(g,nn) holds B[k=kt*32+g*8+s][col=nn]  (same k-map -> cancels)
//   C/D (m89): reg r = C[m=g*4+r][col=nn]
// ---------------------------------------------------------------------------

#define INTERVAL(MM, P, XC, XN) { \
    const int mm = (MM); \
    const bool act = (unsigned)(mm - wv) < (unsigned)NCH; \
    if (wv == 0){ \
        if (mm + 1 < NCH){ \
            _Pragma("unroll") \
            for (int j = 0; j < G; ++j) \
                *(_Float16*)(BB + PH_BASE(0, 1-(P)) + j*128 + (((lane>>3)^(j&7))*16) + (lane&7)*2) = (_Float16)XC[j]; \
        } \
        if (mm + 2 < NCH){ \
            _Pragma("unroll") \
            for (int j = 0; j < G; ++j) \
                XN[j] = x[((size_t)b*TT + (size_t)(mm+2)*G + j)*HH + lane]; \
        } \
    } \
    if (wv == 7 && mm >= 8){ \
        /* y for chunk mm-8, 16 slots: A = h7 slots, B cols all = W_out */ \
        GU ha0, ha1; \
        ha0.h = *(const h8*)(BB + PH_BASE(8, P) + CH_OFF(nn, g)); \
        ha1.h = *(const h8*)(BB + PH_BASE(8, P) + CH_OFF(nn, 4+g)); \
        f32x4 ay = {0.f, 0.f, 0.f, 0.f}; \
        ay = __builtin_amdgcn_mfma_f32_16x16x32_f16(ha0.v, woutB[0].v, ay, 0, 0, 0); \
        ay = __builtin_amdgcn_mfma_f32_16x16x32_f16(ha1.v, woutB[1].v, ay, 0, 0, 0); \
        if (nn == 0){ \
            f32x4 st; \
            st[0] = ay[0] + bout; st[1] = ay[1] + bout; \
            st[2] = ay[2] + bout; st[3] = ay[3] + bout; \
            *(f32x4*)(yout + (size_t)b*TT + (size_t)(mm-8)*G + g*4) = st; \
        } \
    } \
    if (act){ \
        /* ---- x-projection: D[slot m=0..15][w-row t*16+nn], bias in C ---- */ \
        GU bx0, bx1; \
        bx0.h = *(const h8*)(BB + PH_BASE(wv, P) + CH_OFF(nn, g)); \
        bx1.h = *(const h8*)(BB + PH_BASE(wv, P) + CH_OFF(nn, 4+g)); \
        f32x4 xd0 = {bs[0],bs[0],bs[0],bs[0]}, xd1 = {bs[1],bs[1],bs[1],bs[1]}; \
        f32x4 xd2 = {bs[2],bs[2],bs[2],bs[2]}, xd3 = {bs[3],bs[3],bs[3],bs[3]}; \
        xd0 = __builtin_amdgcn_mfma_f32_16x16x32_f16(bx0.v, wihA[0][0].v, xd0, 0, 0, 0); \
        xd0 = __builtin_amdgcn_mfma_f32_16x16x32_f16(bx1.v, wihA[0][1].v, xd0, 0, 0, 0); \
        xd1 = __builtin_amdgcn_mfma_f32_16x16x32_f16(bx0.v, wihA[1][0].v, xd1, 0, 0, 0); \
        xd1 = __builtin_amdgcn_mfma_f32_16x16x32_f16(bx1.v, wihA[1][1].v, xd1, 0, 0, 0); \
        xd2 = __builtin_amdgcn_mfma_f32_16x16x32_f16(bx0.v, wihA[2][0].v, xd2, 0, 0, 0); \
        xd2 = __builtin_amdgcn_mfma_f32_16x16x32_f16(bx1.v, wihA[2][1].v, xd2, 0, 0, 0); \
        xd3 = __builtin_amdgcn_mfma_f32_16x16x32_f16(bx0.v, wihA[3][0].v, xd3, 0, 0, 0); \
        xd3 = __builtin_amdgcn_mfma_f32_16x16x32_f16(bx1.v, wihA[3][1].v, xd3, 0, 0, 0); \
        /* spill: lane(g,nn) batch t regs r -> pre[slot g*4+r][t*16+nn] at [nn][t][g*4] */ \
        *(f32x4*)(preTf + ((size_t)(wv*16+nn)*4 + 0)*PRP + g*4) = xd0; \
        *(f32x4*)(preTf + ((size_t)(wv*16+nn)*4 + 1)*PRP + g*4) = xd1; \
        *(f32x4*)(preTf + ((size_t)(wv*16+nn)*4 + 2)*PRP + g*4) = xd2; \
        *(f32x4*)(preTf + ((size_t)(wv*16+nn)*4 + 3)*PRP + g*4) = xd3; \
        /* readback: lane(g,nn) needs pre[j][g*16+nn] j=0..15 at [nn][g][j] */ \
        f32x4 prv0, prv1, prv2, prv3; \
        { \
            const float* pb = preTf + ((size_t)(wv*16+nn)*4 + g)*PRP; \
            prv0 = *(const f32x4*)(pb);      prv1 = *(const f32x4*)(pb + 4); \
            prv2 = *(const f32x4*)(pb + 8);  prv3 = *(const f32x4*)(pb + 12); \
        } \
        /* ---- 16 serial steps: h-matvec, dep chain = 1 MFMA ---- */ \
        _Pragma("unroll") \
        for (int j = 0; j < G; ++j){ \
            GU hA0, hA1; \
            if (j == 0){ hA0 = hp0; hA1 = hp1; } \
            else { \
                hA0.h = *(const h8*)(BB + PH_BASE(wv+1, 1-(P)) + CH_OFF(j-1, g)); \
                hA1.h = *(const h8*)(BB + PH_BASE(wv+1, 1-(P)) + CH_OFF(j-1, 4+g)); \
            } \
            const f32x4 zz = {0.f, 0.f, 0.f, 0.f}; \
            f32x4 a00 = __builtin_amdgcn_mfma_f32_16x16x32_f16(hA0.v, whhB[0][0].v, zz, 0, 0, 0); \
            f32x4 a01 = __builtin_amdgcn_mfma_f32_16x16x32_f16(hA1.v, whhB[0][1].v, zz, 0, 0, 0); \
            f32x4 a10 = __builtin_amdgcn_mfma_f32_16x16x32_f16(hA0.v, whhB[1][0].v, zz, 0, 0, 0); \
            f32x4 a11 = __builtin_amdgcn_mfma_f32_16x16x32_f16(hA1.v, whhB[1][1].v, zz, 0, 0, 0); \
            f32x4 a20 = __builtin_amdgcn_mfma_f32_16x16x32_f16(hA0.v, whhB[2][0].v, zz, 0, 0, 0); \
            f32x4 a21 = __builtin_amdgcn_mfma_f32_16x16x32_f16(hA1.v, whhB[2][1].v, zz, 0, 0, 0); \
            f32x4 a30 = __builtin_amdgcn_mfma_f32_16x16x32_f16(hA0.v, whhB[3][0].v, zz, 0, 0, 0); \
            f32x4 a31 = __builtin_amdgcn_mfma_f32_16x16x32_f16(hA1.v, whhB[3][1].v, zz, 0, 0, 0); \
            const float s0 = a00[0] + a01[0], s1 = a10[0] + a11[0]; \
            const float s2 = a20[0] + a21[0], s3 = a30[0] + a31[0]; \
            const float pa = (g & 2) ? ((g & 1) ? s3 : s2) : ((g & 1) ? s1 : s0); \
            const float prj = (j < 4) ? prv0[j&3] : (j < 8) ? prv1[j&3] \
                             : (j < 12) ? prv2[j&3] : prv3[j&3]; \
            const float hn = tanh_fast(pa + prj); \
            *(_Float16*)(BB + PH_BASE(wv+1, 1-(P)) + j*128 + (((lane>>3)^(j&7))*16) + (lane&7)*2) = (_Float16)hn; \
            if (j == G-1){ \
                /* prefetch next interval's j=0 A-frags (self-written slot 15) */ \
                hp0.h = *(const h8*)(BB + PH_BASE(wv+1, 1-(P)) + CH_OFF(G-1, g)); \
                hp1.h = *(const h8*)(BB + PH_BASE(wv+1, 1-(P)) + CH_OFF(G-1, 4+g)); \
            } \
            if (mm - wv == NCH-1 && j == G-1) \
                hout[((size_t)wv*NB + b)*HH + lane] = hn; \
        } \
    } \
    barrier_lgkm_only(); \
}

__global__ void __launch_bounds__(512) rnn_kernel(
    const float* __restrict__ x,        // [B,T,64]
    const float* __restrict__ h_state,  // [8,B,64]
    const float* __restrict__ W_ih0,    // [64,64]
    const float* __restrict__ W_ih,     // [7,64,64]
    const float* __restrict__ W_hh,     // [8,64,64]
    const float* __restrict__ b_ih,     // [8,64]
    const float* __restrict__ b_hh,     // [8,64]
    const float* __restrict__ W_out,    // [1,64]
    const float* __restrict__ b_out,    // [1]
    float* __restrict__ out)            // y[256*2048] ++ h_final[8*256*64]
{
    __shared__ __attribute__((aligned(16))) _Float16 buf[(NL+1)*2*G*HH];     // 36 KB
    __shared__ __attribute__((aligned(16))) float preT[NL*16*4*PRP];         // 40 KB
    char* BB = (char*)buf;
    float* preTf = preT;
    const int tid  = threadIdx.x;
    const int wv   = tid >> 6;     // wave id == layer id
    const int lane = tid & 63;
    const int g    = lane >> 4;    // MFMA lane group (k-chunk)
    const int nn   = lane & 15;    // MFMA row-in-tile / column
    const size_t b = blockIdx.x;

    // ---- W_ih / W_hh fragments: lane (g,nn) holds W[t*16+nn][kt*32+g*8 + 0..7]
    GU wihA[4][2], whhB[4][2];
    const float* Wi = (wv == 0) ? W_ih0 : (W_ih + (size_t)(wv-1)*HH*HH);
    const float* Wh = W_hh + (size_t)wv*HH*HH;
    #pragma unroll
    for (int t = 0; t < 4; ++t){
        #pragma unroll
        for (int kt = 0; kt < 2; ++kt){
            const float* pi = Wi + (size_t)(t*16 + nn)*HH + kt*32 + g*8;
            const float* ph = Wh + (size_t)(t*16 + nn)*HH + kt*32 + g*8;
            f32x4 i0 = *(const f32x4*)(pi), i1 = *(const f32x4*)(pi + 4);
            f32x4 h0 = *(const f32x4*)(ph), h1 = *(const f32x4*)(ph + 4);
            wihA[t][kt].p[0] = __builtin_amdgcn_cvt_pkrtz(i0[0], i0[1]);
            wihA[t][kt].p[1] = __builtin_amdgcn_cvt_pkrtz(i0[2], i0[3]);
            wihA[t][kt].p[2] = __builtin_amdgcn_cvt_pkrtz(i1[0], i1[1]);
            wihA[t][kt].p[3] = __builtin_amdgcn_cvt_pkrtz(i1[2], i1[3]);
            whhB[t][kt].p[0] = __builtin_amdgcn_cvt_pkrtz(h0[0], h0[1]);
            whhB[t][kt].p[1] = __builtin_amdgcn_cvt_pkrtz(h0[2], h0[3]);
            whhB[t][kt].p[2] = __builtin_amdgcn_cvt_pkrtz(h1[0], h1[1]);
            whhB[t][kt].p[3] = __builtin_amdgcn_cvt_pkrtz(h1[2], h1[3]);
        }
    }
    // ---- biases per w-row tile: bs[t] for row t*16+nn (flows through preT)
    float bs[4];
    #pragma unroll
    for (int t = 0; t < 4; ++t)
        bs[t] = b_ih[wv*HH + t*16 + nn] + b_hh[wv*HH + t*16 + nn];
    float bout = b_out[0];

    // ---- wave 7: W_out replicated across columns (B[k][c] = W_out[k] for all c)
    GU woutB[2];
    if (wv == 7){
        #pragma unroll
        for (int kt = 0; kt < 2; ++kt)
            #pragma unroll
            for (int q = 0; q < 4; ++q)
                woutB[kt].p[q] = __builtin_amdgcn_cvt_pkrtz(
                    W_out[kt*32 + g*8 + q*2], W_out[kt*32 + g*8 + q*2 + 1]);
    }

    // ---- zero queues, place initial state + first x chunk (swizzled writes)
    for (int i = tid; i < (NL+1)*2*G*HH; i += 512) buf[i] = (_Float16)0.f;
    __syncthreads();
    *(_Float16*)(BB + PH_BASE(wv+1, 1-(wv&1)) + (G-1)*128 + (((lane>>3)^((G-1)&7))*16) + (lane&7)*2)
        = (_Float16)h_state[((size_t)wv*NB + b)*HH + lane];
    float xa[G], xb[G];
    if (wv == 0){
        #pragma unroll
        for (int j = 0; j < G; ++j){
            *(_Float16*)(BB + PH_BASE(0, 1) + j*128 + (((lane>>3)^(j&7))*16) + (lane&7)*2)
                = (_Float16)x[((size_t)b*TT + j)*HH + lane];
            xa[j] = x[((size_t)b*TT + G + j)*HH + lane];
        }
    }
    __syncthreads();

    // ---- prologue prefetch: j=0 A-frags (slot 15 = the h_state just placed;
    //      same-wave DS order guarantees the data)
    GU hp0, hp1;
    hp0.h = *(const h8*)(BB + PH_BASE(wv+1, 1-(wv&1)) + CH_OFF(G-1, g));
    hp1.h = *(const h8*)(BB + PH_BASE(wv+1, 1-(wv&1)) + CH_OFF(G-1, 4+g));

    float* yout = out;                    // [B*T]
    float* hout = out + (size_t)NB*TT;    // [8,B,64]

    for (int m2 = 0; m2 < NI; m2 += 2){
        INTERVAL(m2,     1, xa, xb)
        INTERVAL(m2 + 1, 0, xb, xa)
    }
    // no epilogue: interval NI-1 emits y for the final chunk (all 16 slots)
}

extern "C" void kernel_launch(void* const* d_in, const int* in_sizes, int n_in,
                              void* d_out, int out_size, void* d_ws, size_t ws_size,
                              hipStream_t stream) {
    (void)in_sizes; (void)n_in; (void)d_ws; (void)ws_size; (void)out_size;
    const float* x       = (const float*)d_in[0];
    const float* h_state = (const float*)d_in[1];
    const float* W_ih0   = (const float*)d_in[2];
    const float* W_ih    = (const float*)d_in[3];
    const float* W_hh    = (const float*)d_in[4];
    const float* b_ih    = (const float*)d_in[5];
    const float* b_hh    = (const float*)d_in[6];
    const float* W_out   = (const float*)d_in[7];
    const float* b_out   = (const float*)d_in[8];
    float* out = (float*)d_out;

    rnn_kernel<<<dim3(NB), dim3(512), 0, stream>>>(
        x, h_state, W_ih0, W_ih, W_hh, b_ih, b_hh, W_out, b_out, out);
}

// Round 12
// 479.928 us; speedup vs baseline: 3.5575x; 1.0159x over previous
//
#include <hip/hip_runtime.h>

typedef _Float16 h2 __attribute__((ext_vector_type(2)));
typedef _Float16 h8 __attribute__((ext_vector_type(8)));
typedef __fp16   g2 __attribute__((ext_vector_type(2)));
typedef __fp16   g8 __attribute__((ext_vector_type(8)));
typedef float    f32x4 __attribute__((ext_vector_type(4)));

#define TT 2048
#define HH 64
#define NL 8
#define NB 256
#define G  16           // timesteps per sync interval
#define NCH (TT/G)      // 128 chunks per layer
#define NI  (NCH + NL)  // 136 intervals

#define PRP 20          // preT t-stride (words)
#define NNS 84          // preT nn-stride (words) = 21 16B-chunks (odd -> conflict-free)

union GU { g8 v; g2 p[4]; h8 h; };   // bitcast LDS (_Float16) <-> MFMA (__fp16)

// buf byte layout: boundary l (0..8), phase P (0..1), slot j (0..15), 64 f16.
// Within a slot row (128 B) the 16-B chunk c is stored at index c^(j&7).
#define PH_BASE(l, P) (((l)*2 + (P)) * 2048)
#define CH_OFF(j, c)  ((j)*128 + ((((c) ^ ((j)&7))) * 16))

__device__ __forceinline__ float tanh_fast(float v){
    float e = __expf(2.0f * v);
    float r = __builtin_amdgcn_rcpf(e + 1.0f);
    return fmaf(-2.0f, r, 1.0f);
}

// ---------------------------------------------------------------------------
// R11 structure, barrier REPLACED by producer-consumer LDS flags:
//  - ring dependency only (wave l -> l+1). prodF[l]: boundary l has data for
//    consumer-interval m. consF[l]: consumer finished reading interval m.
//  - producer's data ds_writes precede its flag ds_write (same-wave DS pipe
//    is in-order); consumer's poll-read observing the flag orders its later
//    ds_reads after the data. asm memory fences stop compiler reordering.
//  - self-traffic (wave0 x-staging, wave7 y-queue, preT, recurrence hA) needs
//    no flags at all (same-wave in-order).
//  - waves drift out of lockstep -> DS bursts decorrelate -> lower dependent
//    LDS latency; no 136x barrier drain+skew.
//  - preT re-padded: nn-stride 21 chunks (odd) -> kills the 29.4M conflicts.
// Fragment conventions (R5/R8/R9-verified) unchanged.
// ---------------------------------------------------------------------------

#define INTERVAL(MM, P, XC, XN) { \
    const int mm = (MM); \
    const bool act = (unsigned)(mm - wv) < (unsigned)NCH; \
    if (wv == 0){ \
        if (mm + 1 < NCH){ \
            _Pragma("unroll") \
            for (int j = 0; j < G; ++j) \
                *(_Float16*)(BB + PH_BASE(0, 1-(P)) + j*128 + (((lane>>3)^(j&7))*16) + (lane&7)*2) = (_Float16)XC[j]; \
        } \
        if (mm + 2 < NCH){ \
            _Pragma("unroll") \
            for (int j = 0; j < G; ++j) \
                XN[j] = x[((size_t)b*TT + (size_t)(mm+2)*G + j)*HH + lane]; \
        } \
    } \
    if (wv == 7 && mm >= 8){ \
        /* y for chunk mm-8 (self-written queue, same-wave in-order) */ \
        GU ha0, ha1; \
        ha0.h = *(const h8*)(BB + PH_BASE(8, P) + CH_OFF(nn, g)); \
        ha1.h = *(const h8*)(BB + PH_BASE(8, P) + CH_OFF(nn, 4+g)); \
        f32x4 ay = {0.f, 0.f, 0.f, 0.f}; \
        ay = __builtin_amdgcn_mfma_f32_16x16x32_f16(ha0.v, woutB[0].v, ay, 0, 0, 0); \
        ay = __builtin_amdgcn_mfma_f32_16x16x32_f16(ha1.v, woutB[1].v, ay, 0, 0, 0); \
        if (nn == 0){ \
            f32x4 st; \
            st[0] = ay[0] + bout; st[1] = ay[1] + bout; \
            st[2] = ay[2] + bout; st[3] = ay[3] + bout; \
            *(f32x4*)(yout + (size_t)b*TT + (size_t)(mm-8)*G + g*4) = st; \
        } \
    } \
    if (act){ \
        if (wv > 0){ \
            while (((volatile int*)prodF)[wv] < mm) __builtin_amdgcn_s_sleep(1); \
            asm volatile("" ::: "memory"); \
        } \
        /* ---- x-projection: D[slot][w-row], bias in C ---- */ \
        GU bx0, bx1; \
        bx0.h = *(const h8*)(BB + PH_BASE(wv, P) + CH_OFF(nn, g)); \
        bx1.h = *(const h8*)(BB + PH_BASE(wv, P) + CH_OFF(nn, 4+g)); \
        f32x4 xd0 = {bs[0],bs[0],bs[0],bs[0]}, xd1 = {bs[1],bs[1],bs[1],bs[1]}; \
        f32x4 xd2 = {bs[2],bs[2],bs[2],bs[2]}, xd3 = {bs[3],bs[3],bs[3],bs[3]}; \
        xd0 = __builtin_amdgcn_mfma_f32_16x16x32_f16(bx0.v, wihA[0][0].v, xd0, 0, 0, 0); \
        xd0 = __builtin_amdgcn_mfma_f32_16x16x32_f16(bx1.v, wihA[0][1].v, xd0, 0, 0, 0); \
        xd1 = __builtin_amdgcn_mfma_f32_16x16x32_f16(bx0.v, wihA[1][0].v, xd1, 0, 0, 0); \
        xd1 = __builtin_amdgcn_mfma_f32_16x16x32_f16(bx1.v, wihA[1][1].v, xd1, 0, 0, 0); \
        xd2 = __builtin_amdgcn_mfma_f32_16x16x32_f16(bx0.v, wihA[2][0].v, xd2, 0, 0, 0); \
        xd2 = __builtin_amdgcn_mfma_f32_16x16x32_f16(bx1.v, wihA[2][1].v, xd2, 0, 0, 0); \
        xd3 = __builtin_amdgcn_mfma_f32_16x16x32_f16(bx0.v, wihA[3][0].v, xd3, 0, 0, 0); \
        xd3 = __builtin_amdgcn_mfma_f32_16x16x32_f16(bx1.v, wihA[3][1].v, xd3, 0, 0, 0); \
        /* ack consumption of boundary wv, interval mm (after bx reads, in-order) */ \
        asm volatile("" ::: "memory"); \
        ((volatile int*)consF)[wv] = mm; \
        /* spill / readback (self, in-order; odd chunk strides) */ \
        *(f32x4*)(preTf + (size_t)(wv*16+nn)*NNS + 0*PRP + g*4) = xd0; \
        *(f32x4*)(preTf + (size_t)(wv*16+nn)*NNS + 1*PRP + g*4) = xd1; \
        *(f32x4*)(preTf + (size_t)(wv*16+nn)*NNS + 2*PRP + g*4) = xd2; \
        *(f32x4*)(preTf + (size_t)(wv*16+nn)*NNS + 3*PRP + g*4) = xd3; \
        f32x4 prv0, prv1, prv2, prv3; \
        { \
            const float* pb = preTf + (size_t)(wv*16+nn)*NNS + g*PRP; \
            prv0 = *(const f32x4*)(pb);      prv1 = *(const f32x4*)(pb + 4); \
            prv2 = *(const f32x4*)(pb + 8);  prv3 = *(const f32x4*)(pb + 12); \
        } \
        /* backpressure: consumer of boundary wv+1 must be done with m-1 */ \
        if (wv < 7){ \
            while (((volatile int*)consF)[wv+1] < mm-1) __builtin_amdgcn_s_sleep(1); \
            asm volatile("" ::: "memory"); \
        } \
        /* ---- 16 serial steps (identical to R11) ---- */ \
        _Pragma("unroll") \
        for (int j = 0; j < G; ++j){ \
            GU hA0, hA1; \
            if (j == 0){ hA0 = hp0; hA1 = hp1; } \
            else { \
                hA0.h = *(const h8*)(BB + PH_BASE(wv+1, 1-(P)) + CH_OFF(j-1, g)); \
                hA1.h = *(const h8*)(BB + PH_BASE(wv+1, 1-(P)) + CH_OFF(j-1, 4+g)); \
            } \
            const f32x4 zz = {0.f, 0.f, 0.f, 0.f}; \
            f32x4 a00 = __builtin_amdgcn_mfma_f32_16x16x32_f16(hA0.v, whhB[0][0].v, zz, 0, 0, 0); \
            f32x4 a01 = __builtin_amdgcn_mfma_f32_16x16x32_f16(hA1.v, whhB[0][1].v, zz, 0, 0, 0); \
            f32x4 a10 = __builtin_amdgcn_mfma_f32_16x16x32_f16(hA0.v, whhB[1][0].v, zz, 0, 0, 0); \
            f32x4 a11 = __builtin_amdgcn_mfma_f32_16x16x32_f16(hA1.v, whhB[1][1].v, zz, 0, 0, 0); \
            f32x4 a20 = __builtin_amdgcn_mfma_f32_16x16x32_f16(hA0.v, whhB[2][0].v, zz, 0, 0, 0); \
            f32x4 a21 = __builtin_amdgcn_mfma_f32_16x16x32_f16(hA1.v, whhB[2][1].v, zz, 0, 0, 0); \
            f32x4 a30 = __builtin_amdgcn_mfma_f32_16x16x32_f16(hA0.v, whhB[3][0].v, zz, 0, 0, 0); \
            f32x4 a31 = __builtin_amdgcn_mfma_f32_16x16x32_f16(hA1.v, whhB[3][1].v, zz, 0, 0, 0); \
            const float s0 = a00[0] + a01[0], s1 = a10[0] + a11[0]; \
            const float s2 = a20[0] + a21[0], s3 = a30[0] + a31[0]; \
            const float pa = (g & 2) ? ((g & 1) ? s3 : s2) : ((g & 1) ? s1 : s0); \
            const float prj = (j < 4) ? prv0[j&3] : (j < 8) ? prv1[j&3] \
                             : (j < 12) ? prv2[j&3] : prv3[j&3]; \
            const float hn = tanh_fast(pa + prj); \
            *(_Float16*)(BB + PH_BASE(wv+1, 1-(P)) + j*128 + (((lane>>3)^(j&7))*16) + (lane&7)*2) = (_Float16)hn; \
            if (j == G-1){ \
                hp0.h = *(const h8*)(BB + PH_BASE(wv+1, 1-(P)) + CH_OFF(G-1, g)); \
                hp1.h = *(const h8*)(BB + PH_BASE(wv+1, 1-(P)) + CH_OFF(G-1, 4+g)); \
            } \
            if (mm - wv == NCH-1 && j == G-1) \
                hout[((size_t)wv*NB + b)*HH + lane] = hn; \
        } \
        /* publish: boundary wv+1 data for consumer interval mm+1 is complete */ \
        asm volatile("" ::: "memory"); \
        ((volatile int*)prodF)[wv+1] = mm + 1; \
    } \
}

__global__ void __launch_bounds__(512) rnn_kernel(
    const float* __restrict__ x,        // [B,T,64]
    const float* __restrict__ h_state,  // [8,B,64]
    const float* __restrict__ W_ih0,    // [64,64]
    const float* __restrict__ W_ih,     // [7,64,64]
    const float* __restrict__ W_hh,     // [8,64,64]
    const float* __restrict__ b_ih,     // [8,64]
    const float* __restrict__ b_hh,     // [8,64]
    const float* __restrict__ W_out,    // [1,64]
    const float* __restrict__ b_out,    // [1]
    float* __restrict__ out)            // y[256*2048] ++ h_final[8*256*64]
{
    __shared__ __attribute__((aligned(16))) _Float16 buf[(NL+1)*2*G*HH];     // 36 KB
    __shared__ __attribute__((aligned(16))) float preT[NL*16*NNS];           // 42 KB
    __shared__ int prodF[16];
    __shared__ int consF[16];
    char* BB = (char*)buf;
    float* preTf = preT;
    const int tid  = threadIdx.x;
    const int wv   = tid >> 6;     // wave id == layer id
    const int lane = tid & 63;
    const int g    = lane >> 4;    // MFMA lane group (k-chunk)
    const int nn   = lane & 15;    // MFMA row-in-tile / column
    const size_t b = blockIdx.x;

    // ---- W_ih / W_hh fragments: lane (g,nn) holds W[t*16+nn][kt*32+g*8 + 0..7]
    GU wihA[4][2], whhB[4][2];
    const float* Wi = (wv == 0) ? W_ih0 : (W_ih + (size_t)(wv-1)*HH*HH);
    const float* Wh = W_hh + (size_t)wv*HH*HH;
    #pragma unroll
    for (int t = 0; t < 4; ++t){
        #pragma unroll
        for (int kt = 0; kt < 2; ++kt){
            const float* pi = Wi + (size_t)(t*16 + nn)*HH + kt*32 + g*8;
            const float* ph = Wh + (size_t)(t*16 + nn)*HH + kt*32 + g*8;
            f32x4 i0 = *(const f32x4*)(pi), i1 = *(const f32x4*)(pi + 4);
            f32x4 h0 = *(const f32x4*)(ph), h1 = *(const f32x4*)(ph + 4);
            wihA[t][kt].p[0] = __builtin_amdgcn_cvt_pkrtz(i0[0], i0[1]);
            wihA[t][kt].p[1] = __builtin_amdgcn_cvt_pkrtz(i0[2], i0[3]);
            wihA[t][kt].p[2] = __builtin_amdgcn_cvt_pkrtz(i1[0], i1[1]);
            wihA[t][kt].p[3] = __builtin_amdgcn_cvt_pkrtz(i1[2], i1[3]);
            whhB[t][kt].p[0] = __builtin_amdgcn_cvt_pkrtz(h0[0], h0[1]);
            whhB[t][kt].p[1] = __builtin_amdgcn_cvt_pkrtz(h0[2], h0[3]);
            whhB[t][kt].p[2] = __builtin_amdgcn_cvt_pkrtz(h1[0], h1[1]);
            whhB[t][kt].p[3] = __builtin_amdgcn_cvt_pkrtz(h1[2], h1[3]);
        }
    }
    // ---- biases per w-row tile: bs[t] for row t*16+nn (flows through preT)
    float bs[4];
    #pragma unroll
    for (int t = 0; t < 4; ++t)
        bs[t] = b_ih[wv*HH + t*16 + nn] + b_hh[wv*HH + t*16 + nn];
    float bout = b_out[0];

    // ---- wave 7: W_out replicated across columns (B[k][c] = W_out[k] for all c)
    GU woutB[2];
    if (wv == 7){
        #pragma unroll
        for (int kt = 0; kt < 2; ++kt)
            #pragma unroll
            for (int q = 0; q < 4; ++q)
                woutB[kt].p[q] = __builtin_amdgcn_cvt_pkrtz(
                    W_out[kt*32 + g*8 + q*2], W_out[kt*32 + g*8 + q*2 + 1]);
    }

    // ---- zero queues, init flags, place initial state + first x chunk
    for (int i = tid; i < (NL+1)*2*G*HH; i += 512) buf[i] = (_Float16)0.f;
    if (tid < 16){
        prodF[tid] = 0;          // consumer w polls >= m (m >= 1 at first use)
        consF[tid] = tid - 2;    // producer w polls consF[w+1] >= m-1; init = (w+1)-2
    }
    __syncthreads();
    *(_Float16*)(BB + PH_BASE(wv+1, 1-(wv&1)) + (G-1)*128 + (((lane>>3)^((G-1)&7))*16) + (lane&7)*2)
        = (_Float16)h_state[((size_t)wv*NB + b)*HH + lane];
    float xa[G], xb[G];
    if (wv == 0){
        #pragma unroll
        for (int j = 0; j < G; ++j){
            *(_Float16*)(BB + PH_BASE(0, 1) + j*128 + (((lane>>3)^(j&7))*16) + (lane&7)*2)
                = (_Float16)x[((size_t)b*TT + j)*HH + lane];
            xa[j] = x[((size_t)b*TT + G + j)*HH + lane];
        }
    }
    __syncthreads();

    // ---- prologue prefetch: j=0 A-frags (slot 15 = h_state; same-wave order)
    GU hp0, hp1;
    hp0.h = *(const h8*)(BB + PH_BASE(wv+1, 1-(wv&1)) + CH_OFF(G-1, g));
    hp1.h = *(const h8*)(BB + PH_BASE(wv+1, 1-(wv&1)) + CH_OFF(G-1, 4+g));

    float* yout = out;                    // [B*T]
    float* hout = out + (size_t)NB*TT;    // [8,B,64]

    for (int m2 = 0; m2 < NI; m2 += 2){
        INTERVAL(m2,     1, xa, xb)
        INTERVAL(m2 + 1, 0, xb, xa)
    }
    // no epilogue: interval NI-1 emits y for the final chunk (all 16 slots)
}

extern "C" void kernel_launch(void* const* d_in, const int* in_sizes, int n_in,
                              void* d_out, int out_size, void* d_ws, size_t ws_size,
                              hipStream_t stream) {
    (void)in_sizes; (void)n_in; (void)d_ws; (void)ws_size; (void)out_size;
    const float* x       = (const float*)d_in[0];
    const float* h_state = (const float*)d_in[1];
    const float* W_ih0   = (const float*)d_in[2];
    const float* W_ih    = (const float*)d_in[3];
    const float* W_hh    = (const float*)d_in[4];
    const float* b_ih    = (const float*)d_in[5];
    const float* b_hh    = (const float*)d_in[6];
    const float* W_out   = (const float*)d_in[7];
    const float* b_out   = (const float*)d_in[8];
    float* out = (float*)d_out;

    rnn_kernel<<<dim3(NB), dim3(512), 0, stream>>>(
        x, h_state, W_ih0, W_ih, W_hh, b_ih, b_hh, W_out, b_out, out);
}